// Round 2
// baseline (1650.381 us; speedup 1.0000x reference)
//
#include <hip/hip_runtime.h>

#define B_ 4
#define C_ 192
#define H_ 128
#define W_ 128
#define N_ (H_*W_)      // 16384
#define K_ 2048
#define HEADS_ 3
#define HD_ 64
#define HID_ 768

__device__ __forceinline__ unsigned short f2bf(float f){
  unsigned int u = __float_as_uint(f);
  u += 0x7FFFu + ((u >> 16) & 1u);
  return (unsigned short)(u >> 16);
}
__device__ __forceinline__ float bf2f(unsigned short s){
  return __uint_as_float(((unsigned int)s) << 16);
}

// indices may arrive as int32 or int64. Sorted-unique ascending indices =>
// u32 words 1,3,5,7 are nonzero iff storage is int32 (int64 high words are 0).
__device__ __forceinline__ int load_idx(const unsigned* __restrict__ ip, int pos){
  bool is64 = (ip[1]==0u) & (ip[3]==0u) & (ip[5]==0u) & (ip[7]==0u);
  int v = is64 ? (int)ip[2*pos] : (int)ip[pos];
  return min(max(v, 0), N_-1);
}

// ---------------- LN1: x (B,C,N) -> y (nb,N,C) ----------------
__global__ __launch_bounds__(64) void k_ln1(const float* __restrict__ x,
    const float* __restrict__ w, const float* __restrict__ bias,
    float* __restrict__ y, int b_off){
  int blk = blockIdx.x;
  int bl = blk / (N_/64);
  int b  = b_off + bl;
  int n0 = (blk % (N_/64)) * 64;
  int t  = threadIdx.x;
  __shared__ float tile[64][C_+1];
  const float* xb = x + (size_t)b*C_*N_ + n0;
  float sum = 0.f, sq = 0.f;
  for (int c = 0; c < C_; ++c){
    float v = xb[(size_t)c*N_ + t];
    tile[t][c] = v;
    sum += v; sq += v*v;
  }
  float mu = sum * (1.f/C_);
  float rstd = rsqrtf(sq*(1.f/C_) - mu*mu + 1e-5f);
  for (int c = 0; c < C_; ++c)
    tile[t][c] = (tile[t][c]-mu)*rstd*w[c] + bias[c];
  __syncthreads();
  float* yb = y + ((size_t)bl*N_ + n0)*C_;
  for (int tok = 0; tok < 64; ++tok){
#pragma unroll
    for (int j = 0; j < 3; ++j)
      yb[tok*C_ + j*64 + t] = tile[tok][j*64 + t];
  }
}

// ---------------- QKV GEMM with gather: (nb,K,576) ----------------
__global__ __launch_bounds__(256) void k_qkv(const float* __restrict__ y,
    const unsigned* __restrict__ idx, const float* __restrict__ wq,
    float* __restrict__ qkv, int b_off){
  const int NT = (3*C_)/64;            // 9
  int bid = blockIdx.x;
  int bl  = bid / ((K_/64)*NT);
  int rem = bid % ((K_/64)*NT);
  int m0  = (rem / NT) * 64;
  int n0  = (rem % NT) * 64;
  int tid = threadIdx.x;
  __shared__ float As[64][17];
  __shared__ float Bs[64][17];
  __shared__ int rows[64];
  if (tid < 64) rows[tid] = load_idx(idx, (b_off+bl)*K_ + m0 + tid);
  __syncthreads();
  int tn = tid % 16, tm = tid / 16;
  float acc[4][4] = {};
  for (int k0 = 0; k0 < C_; k0 += 16){
#pragma unroll
    for (int i = 0; i < 4; ++i){
      int li = tid + 256*i; int kk = li % 16, m = li / 16;
      As[m][kk] = y[((size_t)bl*N_ + rows[m])*C_ + k0 + kk];
    }
#pragma unroll
    for (int i = 0; i < 4; ++i){
      int li = tid + 256*i; int kk = li % 16, nn = li / 16;
      Bs[nn][kk] = wq[(size_t)(n0+nn)*C_ + k0 + kk];
    }
    __syncthreads();
#pragma unroll
    for (int kk = 0; kk < 16; ++kk){
      float a[4], bb[4];
#pragma unroll
      for (int i=0;i<4;++i) a[i] = As[tm*4+i][kk];
#pragma unroll
      for (int j=0;j<4;++j) bb[j] = Bs[tn*4+j][kk];
#pragma unroll
      for (int i=0;i<4;++i)
#pragma unroll
        for (int j=0;j<4;++j) acc[i][j] += a[i]*bb[j];
    }
    __syncthreads();
  }
  float* op = qkv + ((size_t)bl*K_ + m0)*(3*C_) + n0;
#pragma unroll
  for (int i = 0; i < 4; ++i){
    float4 v = make_float4(acc[i][0], acc[i][1], acc[i][2], acc[i][3]);
    *reinterpret_cast<float4*>(op + (size_t)(tm*4+i)*(3*C_) + tn*4) = v;
  }
}

// ---------------- attention: flash over K, block=(bl,h,64 q rows) ----------------
__global__ __launch_bounds__(256) void k_attn(const float* __restrict__ qkv,
    float* __restrict__ ao){
  int bid = blockIdx.x;
  int q0  = (bid % (K_/64)) * 64;
  int bh  = bid / (K_/64);
  int h = bh % HEADS_, bl = bh / HEADS_;
  __shared__ float Ks[64][68];
  __shared__ float Vs[64][68];
  __shared__ float Ss[64][68];      // Q staging, then P
  int tid = threadIdx.x;
  const float* base = qkv + (size_t)bl*K_*(3*C_) + h*HD_;
#pragma unroll
  for (int i = 0; i < 4; ++i){
    int li = tid + 256*i;            // 1024 float4 slots
    int d4 = li & 15, r = li >> 4;
    reinterpret_cast<float4*>(&Ss[r][0])[d4] =
        *reinterpret_cast<const float4*>(base + (size_t)(q0+r)*(3*C_) + 4*d4);
  }
  __syncthreads();
  int r = tid >> 2, g = tid & 3;
  float qreg[HD_];
#pragma unroll
  for (int d = 0; d < HD_; ++d) qreg[d] = Ss[r][d];
  __syncthreads();
  float m_r = -1e30f, l_r = 0.f, acc[16];
#pragma unroll
  for (int i=0;i<16;++i) acc[i]=0.f;
  for (int k0 = 0; k0 < K_; k0 += 64){
#pragma unroll
    for (int i = 0; i < 4; ++i){
      int li = tid + 256*i;
      int d4 = li & 15, rr = li >> 4;
      reinterpret_cast<float4*>(&Ks[rr][0])[d4] =
          *reinterpret_cast<const float4*>(base + (size_t)(k0+rr)*(3*C_) + C_   + 4*d4);
      reinterpret_cast<float4*>(&Vs[rr][0])[d4] =
          *reinterpret_cast<const float4*>(base + (size_t)(k0+rr)*(3*C_) + 2*C_ + 4*d4);
    }
    __syncthreads();
    float sv[16], smax = -1e30f;
#pragma unroll
    for (int i = 0; i < 16; ++i){
      int j = g + 4*i;
      const float4* kr = reinterpret_cast<const float4*>(&Ks[j][0]);
      float s = 0.f;
#pragma unroll
      for (int d4 = 0; d4 < 16; ++d4){
        float4 kv = kr[d4];
        s += qreg[4*d4]*kv.x + qreg[4*d4+1]*kv.y + qreg[4*d4+2]*kv.z + qreg[4*d4+3]*kv.w;
      }
      s *= 0.125f;
      sv[i] = s;
      smax = fmaxf(smax, s);
    }
    smax = fmaxf(smax, __shfl_xor(smax, 1));
    smax = fmaxf(smax, __shfl_xor(smax, 2));
    float m_new = fmaxf(m_r, smax);
    float corr = __expf(m_r - m_new);
    float ps = 0.f;
#pragma unroll
    for (int i = 0; i < 16; ++i){
      float p = __expf(sv[i] - m_new);
      Ss[r][g + 4*i] = p;
      ps += p;
    }
    ps += __shfl_xor(ps, 1);
    ps += __shfl_xor(ps, 2);
    l_r = l_r*corr + ps;
    m_r = m_new;
    __syncthreads();
#pragma unroll
    for (int i=0;i<16;++i) acc[i] *= corr;
    for (int j = 0; j < 64; ++j){
      float p = Ss[r][j];
      const float4* vr = reinterpret_cast<const float4*>(&Vs[j][g*16]);
#pragma unroll
      for (int i4 = 0; i4 < 4; ++i4){
        float4 vv = vr[i4];
        acc[4*i4]   += p*vv.x; acc[4*i4+1] += p*vv.y;
        acc[4*i4+2] += p*vv.z; acc[4*i4+3] += p*vv.w;
      }
    }
    __syncthreads();
  }
  float inv = 1.f / l_r;
  float* op = ao + ((size_t)bl*K_ + q0 + r)*C_ + h*HD_ + g*16;
#pragma unroll
  for (int i = 0; i < 16; ++i) op[i] = acc[i]*inv;
}

// ---------------- proj GEMM + scatter into y ----------------
__global__ __launch_bounds__(256) void k_proj(const float* __restrict__ ain,
    const unsigned* __restrict__ idx, const float* __restrict__ pw,
    const float* __restrict__ pb, float* __restrict__ y, int b_off){
  const int NT = C_/64;               // 3
  int bid = blockIdx.x;
  int bl  = bid / ((K_/64)*NT);
  int rem = bid % ((K_/64)*NT);
  int m0  = (rem / NT)*64;
  int n0  = (rem % NT)*64;
  int tid = threadIdx.x;
  __shared__ float As[64][17];
  __shared__ float Bs[64][17];
  __shared__ int rows[64];
  if (tid < 64) rows[tid] = load_idx(idx, (b_off+bl)*K_ + m0 + tid);
  __syncthreads();
  int tn = tid % 16, tm = tid / 16;
  float acc[4][4] = {};
  for (int k0 = 0; k0 < C_; k0 += 16){
#pragma unroll
    for (int i = 0; i < 4; ++i){
      int li = tid + 256*i; int kk = li % 16, m = li / 16;
      As[m][kk] = ain[((size_t)bl*K_ + m0 + m)*C_ + k0 + kk];
    }
#pragma unroll
    for (int i = 0; i < 4; ++i){
      int li = tid + 256*i; int kk = li % 16, nn = li / 16;
      Bs[nn][kk] = pw[(size_t)(n0+nn)*C_ + k0 + kk];
    }
    __syncthreads();
#pragma unroll
    for (int kk = 0; kk < 16; ++kk){
      float a[4], bb[4];
#pragma unroll
      for (int i=0;i<4;++i) a[i] = As[tm*4+i][kk];
#pragma unroll
      for (int j=0;j<4;++j) bb[j] = Bs[tn*4+j][kk];
#pragma unroll
      for (int i=0;i<4;++i)
#pragma unroll
        for (int j=0;j<4;++j) acc[i][j] += a[i]*bb[j];
    }
    __syncthreads();
  }
  float b0 = pb[n0+tn*4], b1 = pb[n0+tn*4+1], b2 = pb[n0+tn*4+2], b3 = pb[n0+tn*4+3];
#pragma unroll
  for (int i = 0; i < 4; ++i){
    float* dst = y + ((size_t)bl*N_ + rows[tm*4+i])*C_ + n0 + tn*4;
    float4 v = make_float4(acc[i][0]+b0, acc[i][1]+b1, acc[i][2]+b2, acc[i][3]+b3);
    *reinterpret_cast<float4*>(dst) = v;
  }
}

// ---------------- residual + LN2: -> ln2t (B,C,N)  [ln2t == d_out] ----------------
__global__ __launch_bounds__(64) void k_ln2(const float* __restrict__ x,
    const float* __restrict__ y, const float* __restrict__ w,
    const float* __restrict__ bias, float* __restrict__ ln2t, int b_off){
  int blk = blockIdx.x;
  int bl = blk / (N_/64);
  int b  = b_off + bl;
  int n0 = (blk % (N_/64)) * 64;
  int t  = threadIdx.x;
  __shared__ float tile[64][C_+1];
  const float* yb = y + ((size_t)bl*N_ + n0)*C_;
  for (int i = 0; i < C_; ++i){       // 64*192 contiguous floats
    int li = t + 64*i;
    tile[li/C_][li%C_] = yb[li];
  }
  __syncthreads();
  const float* xb = x + (size_t)b*C_*N_ + n0;
  float sum = 0.f, sq = 0.f;
  for (int c = 0; c < C_; ++c){
    float v = xb[(size_t)c*N_ + t] + tile[t][c];
    tile[t][c] = v;
    sum += v; sq += v*v;
  }
  float mu = sum * (1.f/C_);
  float rstd = rsqrtf(sq*(1.f/C_) - mu*mu + 1e-5f);
  for (int c = 0; c < C_; ++c)
    tile[t][c] = (tile[t][c]-mu)*rstd*w[c] + bias[c];
  __syncthreads();
  float* ob = ln2t + (size_t)b*C_*N_ + n0;
  for (int c = 0; c < C_; ++c)
    ob[(size_t)c*N_ + t] = tile[t][c];
}

// ---------------- fc1 (one batch): a (C,N) @ fc1_w^T -> h1 bf16 (HID,N) ----------------
__global__ __launch_bounds__(256) void k_fc1(const float* __restrict__ a,
    const float* __restrict__ wgt, const float* __restrict__ bias,
    unsigned short* __restrict__ h1){
  const int NT = HID_/64;             // 12
  int bid = blockIdx.x;
  int m0  = (bid / NT)*64;
  int n0  = (bid % NT)*64;
  int tid = threadIdx.x;
  __shared__ float As[64][17];
  __shared__ float Bs[64][17];
  int tm = tid % 16, tn = tid / 16;
  float acc[4][4] = {};
  const float* ab = a + m0;
  for (int k0 = 0; k0 < C_; k0 += 16){
#pragma unroll
    for (int i = 0; i < 4; ++i){
      int li = tid + 256*i; int m = li % 64, kk = li / 64;
      As[m][kk] = ab[(size_t)(k0+kk)*N_ + m];
    }
#pragma unroll
    for (int i = 0; i < 4; ++i){
      int li = tid + 256*i; int kk = li % 16, nn = li / 16;
      Bs[nn][kk] = wgt[(size_t)(n0+nn)*C_ + k0 + kk];
    }
    __syncthreads();
#pragma unroll
    for (int kk = 0; kk < 16; ++kk){
      float av[4], bb[4];
#pragma unroll
      for (int i=0;i<4;++i) av[i] = As[tm*4+i][kk];
#pragma unroll
      for (int j=0;j<4;++j) bb[j] = Bs[tn*4+j][kk];
#pragma unroll
      for (int i=0;i<4;++i)
#pragma unroll
        for (int j=0;j<4;++j) acc[i][j] += av[i]*bb[j];
    }
    __syncthreads();
  }
#pragma unroll
  for (int j = 0; j < 4; ++j){
    int hid = n0 + tn*4 + j;
    float bv = bias[hid];
    ushort4 pk;
    pk.x = f2bf(acc[0][j]+bv); pk.y = f2bf(acc[1][j]+bv);
    pk.z = f2bf(acc[2][j]+bv); pk.w = f2bf(acc[3][j]+bv);
    *reinterpret_cast<ushort4*>(h1 + (size_t)hid*N_ + m0 + tm*4) = pk;
  }
}

// ---------------- depthwise 3x3 + exact GELU (one batch) ----------------
__global__ __launch_bounds__(256) void k_conv(const unsigned short* __restrict__ h1,
    const float* __restrict__ dw, unsigned short* __restrict__ g){
  size_t gid = (size_t)blockIdx.x*256 + threadIdx.x;
  int ww = (int)(gid % W_);
  int hh = (int)((gid / W_) % H_);
  int ch = (int)(gid / N_);
  const unsigned short* plane = h1 + (size_t)ch*N_;
  const float* wv = dw + (size_t)ch*9;
  float s = 0.f;
#pragma unroll
  for (int ky = 0; ky < 3; ++ky){
    int yy = hh + ky - 1;
    if (yy < 0 || yy >= H_) continue;
#pragma unroll
    for (int kx = 0; kx < 3; ++kx){
      int xx = ww + kx - 1;
      if (xx < 0 || xx >= W_) continue;
      s += bf2f(plane[yy*W_ + xx]) * wv[ky*3+kx];
    }
  }
  float ge = 0.5f*s*(1.f + erff(s*0.70710678f));
  g[gid] = f2bf(ge);
}

// ---------------- fc2 + bias + residual (one batch), io = ln2t[b] = out[b] ----------------
__global__ __launch_bounds__(256) void k_fc2(const unsigned short* __restrict__ g,
    const float* __restrict__ wgt, const float* __restrict__ bias,
    float* io){
  const int NT = C_/64;               // 3
  int bid = blockIdx.x;
  int m0  = (bid / NT)*64;
  int n0  = (bid % NT)*64;
  int tid = threadIdx.x;
  __shared__ float As[64][17];
  __shared__ float Bs[64][17];
  int tm = tid % 16, tn = tid / 16;
  float acc[4][4] = {};
  const unsigned short* gb = g + m0;
  for (int k0 = 0; k0 < HID_; k0 += 16){
#pragma unroll
    for (int i = 0; i < 4; ++i){
      int li = tid + 256*i; int m = li % 64, kk = li / 64;
      As[m][kk] = bf2f(gb[(size_t)(k0+kk)*N_ + m]);
    }
#pragma unroll
    for (int i = 0; i < 4; ++i){
      int li = tid + 256*i; int kk = li % 16, nn = li / 16;
      Bs[nn][kk] = wgt[(size_t)(n0+nn)*HID_ + k0 + kk];
    }
    __syncthreads();
#pragma unroll
    for (int kk = 0; kk < 16; ++kk){
      float av[4], bb[4];
#pragma unroll
      for (int i=0;i<4;++i) av[i] = As[tm*4+i][kk];
#pragma unroll
      for (int j=0;j<4;++j) bb[j] = Bs[tn*4+j][kk];
#pragma unroll
      for (int i=0;i<4;++i)
#pragma unroll
        for (int j=0;j<4;++j) acc[i][j] += av[i]*bb[j];
    }
    __syncthreads();
  }
#pragma unroll
  for (int j = 0; j < 4; ++j){
    int c = n0 + tn*4 + j;
    float bv = bias[c];
    size_t off = (size_t)c*N_ + m0 + tm*4;
    float4 rr = *reinterpret_cast<const float4*>(io + off);
    float4 v = make_float4(rr.x + acc[0][j] + bv, rr.y + acc[1][j] + bv,
                           rr.z + acc[2][j] + bv, rr.w + acc[3][j] + bv);
    *reinterpret_cast<float4*>(io + off) = v;
  }
}

extern "C" void kernel_launch(void* const* d_in, const int* in_sizes, int n_in,
                              void* d_out, int out_size, void* d_ws, size_t ws_size,
                              hipStream_t stream) {
  const float*    x      = (const float*)d_in[0];
  const unsigned* idx    = (const unsigned*)d_in[1];
  const float*    ln1_w  = (const float*)d_in[2];
  const float*    ln1_b  = (const float*)d_in[3];
  const float*    qkv_w  = (const float*)d_in[4];
  const float*    proj_w = (const float*)d_in[5];
  const float*    proj_b = (const float*)d_in[6];
  const float*    ln2_w  = (const float*)d_in[7];
  const float*    ln2_b  = (const float*)d_in[8];
  const float*    fc1_w  = (const float*)d_in[9];
  const float*    fc1_b  = (const float*)d_in[10];
  const float*    dw_w   = (const float*)d_in[11];
  const float*    fc2_w  = (const float*)d_in[12];
  const float*    fc2_b  = (const float*)d_in[13];
  float* out = (float*)d_out;          // doubles as ln2t (B,C,N) f32

  // per-chunk scratch sizes (nb batches in flight for the attention phase)
  const size_t SZ_H1 = (size_t)HID_*N_*2;                 // 25.2 MB (one batch)
  auto need = [&](int nb)->size_t{
    size_t szY = (size_t)nb*N_*C_*4;
    size_t szQ = (size_t)nb*K_*3*C_*4;
    size_t szA = (size_t)nb*K_*C_*4;
    size_t tail = szQ + szA; if (tail < 2*SZ_H1) tail = 2*SZ_H1;
    return szY + tail;
  };
  int nb = (ws_size >= need(B_)) ? B_ : 1;   // deterministic: ws_size is fixed

  char* ws = (char*)d_ws;
  size_t szY = (size_t)nb*N_*C_*4;
  size_t szQ = (size_t)nb*K_*3*C_*4;
  float* y    = (float*)ws;
  float* qkvb = (float*)(ws + szY);
  float* aob  = (float*)(ws + szY + szQ);
  // h1/g reuse the qkv/ao region (dead by the time fc1 runs)
  unsigned short* h1 = (unsigned short*)(ws + szY);
  unsigned short* gg = h1 + (size_t)HID_*N_;

  for (int b0 = 0; b0 < B_; b0 += nb){
    k_ln1 <<<nb*(N_/64),             64, 0, stream>>>(x, ln1_w, ln1_b, y, b0);
    k_qkv <<<nb*(K_/64)*((3*C_)/64),256, 0, stream>>>(y, idx, qkv_w, qkvb, b0);
    k_attn<<<nb*HEADS_*(K_/64),     256, 0, stream>>>(qkvb, aob);
    k_proj<<<nb*(K_/64)*(C_/64),    256, 0, stream>>>(aob, idx, proj_w, proj_b, y, b0);
    k_ln2 <<<nb*(N_/64),             64, 0, stream>>>(x, y, ln2_w, ln2_b, out, b0);
    for (int b = b0; b < b0 + nb; ++b){
      const float* ln2b = out + (size_t)b*C_*N_;
      k_fc1 <<<(N_/64)*(HID_/64), 256, 0, stream>>>(ln2b, fc1_w, fc1_b, h1);
      k_conv<<<(int)(((size_t)HID_*N_)/256), 256, 0, stream>>>(h1, dw_w, gg);
      k_fc2 <<<(N_/64)*(C_/64),   256, 0, stream>>>(gg, fc2_w, fc2_b,
                                                    out + (size_t)b*C_*N_);
    }
  }
}

// Round 3
// 738.389 us; speedup vs baseline: 2.2351x; 2.2351x over previous
//
#include <hip/hip_runtime.h>

#define B_ 4
#define C_ 192
#define H_ 128
#define W_ 128
#define N_ (H_*W_)      // 16384
#define K_ 2048
#define HEADS_ 3
#define HD_ 64
#define HID_ 768

typedef __attribute__((ext_vector_type(4))) float f32x4;
typedef __attribute__((ext_vector_type(8))) short bf16x8;

__device__ __forceinline__ unsigned short f2bf(float f){
  unsigned int u = __float_as_uint(f);
  u += 0x7FFFu + ((u >> 16) & 1u);
  return (unsigned short)(u >> 16);
}
__device__ __forceinline__ float bf2f(unsigned short s){
  return __uint_as_float(((unsigned int)s) << 16);
}

// indices may arrive as int32 or int64. Sorted-unique ascending indices =>
// u32 words 1,3,5,7 are nonzero iff storage is int32 (int64 high words are 0).
__device__ __forceinline__ int load_idx(const unsigned* __restrict__ ip, int pos){
  bool is64 = (ip[1]==0u) & (ip[3]==0u) & (ip[5]==0u) & (ip[7]==0u);
  int v = is64 ? (int)ip[2*pos] : (int)ip[pos];
  return min(max(v, 0), N_-1);
}

// ---------------- LN1: x (B,C,N) -> y (nb,N,C) fp32 ----------------
__global__ __launch_bounds__(64) void k_ln1(const float* __restrict__ x,
    const float* __restrict__ w, const float* __restrict__ bias,
    float* __restrict__ y, int b_off){
  int blk = blockIdx.x;
  int bl = blk / (N_/64);
  int b  = b_off + bl;
  int n0 = (blk % (N_/64)) * 64;
  int t  = threadIdx.x;
  __shared__ float tile[64][C_+1];
  const float* xb = x + (size_t)b*C_*N_ + n0;
  float sum = 0.f, sq = 0.f;
  for (int c = 0; c < C_; ++c){
    float v = xb[(size_t)c*N_ + t];
    tile[t][c] = v;
    sum += v; sq += v*v;
  }
  float mu = sum * (1.f/C_);
  float rstd = rsqrtf(sq*(1.f/C_) - mu*mu + 1e-5f);
  for (int c = 0; c < C_; ++c)
    tile[t][c] = (tile[t][c]-mu)*rstd*w[c] + bias[c];
  __syncthreads();
  float* yb = y + ((size_t)bl*N_ + n0)*C_;
  for (int tok = 0; tok < 64; ++tok){
#pragma unroll
    for (int j = 0; j < 3; ++j)
      yb[tok*C_ + j*64 + t] = tile[tok][j*64 + t];
  }
}

// ---------------- QKV MFMA GEMM with gather: y fp32 -> qkv bf16 (bl,K,576) ----------------
__global__ __launch_bounds__(256) void k_qkv(const float* __restrict__ y,
    const unsigned* __restrict__ idx, const float* __restrict__ wq,
    unsigned short* __restrict__ qkv, int b_off){
  const int MT = K_/128, NT = (3*C_)/64;  // 16, 9
  int bid = blockIdx.x;
  int bl  = bid / (MT*NT);
  int rem = bid % (MT*NT);
  int m0  = (rem / NT) * 128;
  int n0  = (rem % NT) * 64;
  int t = threadIdx.x, lane = t & 63;
  int wv = t >> 6, wm = wv & 1, wn = wv >> 1;
  __shared__ unsigned short Al[128][40];
  __shared__ unsigned short Bl[64][40];
  __shared__ int rows[128];
  if (t < 128) rows[t] = load_idx(idx, (b_off+bl)*K_ + m0 + t);
  __syncthreads();
  f32x4 acc[4][2] = {};
  int l15 = lane & 15, lhi = lane >> 4;
  for (int k0 = 0; k0 < C_; k0 += 32){
    {
      int m = t >> 1;
      const float* src = y + ((size_t)bl*N_ + rows[m])*C_ + k0;
#pragma unroll
      for (int i = 0; i < 4; ++i){
        int kq = (t & 1) + 2*i;
        float4 v = *reinterpret_cast<const float4*>(src + 4*kq);
        ushort4 p; p.x=f2bf(v.x); p.y=f2bf(v.y); p.z=f2bf(v.z); p.w=f2bf(v.w);
        *reinterpret_cast<ushort4*>(&Al[m][4*kq]) = p;
      }
      int n = t >> 2;
      const float* bsrc = wq + (size_t)(n0+n)*C_ + k0;
#pragma unroll
      for (int i = 0; i < 2; ++i){
        int q = (t & 3) + 4*i;
        float4 v = *reinterpret_cast<const float4*>(bsrc + 4*q);
        ushort4 p; p.x=f2bf(v.x); p.y=f2bf(v.y); p.z=f2bf(v.z); p.w=f2bf(v.w);
        *reinterpret_cast<ushort4*>(&Bl[n][4*q]) = p;
      }
    }
    __syncthreads();
    bf16x8 af[4], bfr[2];
#pragma unroll
    for (int mf = 0; mf < 4; ++mf)
      af[mf] = *reinterpret_cast<const bf16x8*>(&Al[wm*64 + mf*16 + l15][lhi*8]);
#pragma unroll
    for (int nf = 0; nf < 2; ++nf)
      bfr[nf] = *reinterpret_cast<const bf16x8*>(&Bl[wn*32 + nf*16 + l15][lhi*8]);
#pragma unroll
    for (int mf = 0; mf < 4; ++mf)
#pragma unroll
      for (int nf = 0; nf < 2; ++nf)
        acc[mf][nf] = __builtin_amdgcn_mfma_f32_16x16x32_bf16(af[mf], bfr[nf], acc[mf][nf], 0,0,0);
    __syncthreads();
  }
#pragma unroll
  for (int mf = 0; mf < 4; ++mf){
    int mb = m0 + wm*64 + mf*16 + lhi*4;
#pragma unroll
    for (int nf = 0; nf < 2; ++nf){
      int n = n0 + wn*32 + nf*16 + l15;
#pragma unroll
      for (int r = 0; r < 4; ++r)
        qkv[((size_t)bl*K_ + mb + r)*(3*C_) + n] = f2bf(acc[mf][nf][r]);
    }
  }
}

// ---------------- attention: flash MFMA, block=(bl,h,64 q rows), 4 waves ----------------
__global__ __launch_bounds__(256) void k_attn(const unsigned short* __restrict__ qkv,
    unsigned short* __restrict__ ao){
  int bid = blockIdx.x;
  int q0  = (bid % (K_/64)) * 64;
  int bh  = bid / (K_/64);
  int h = bh % HEADS_, bl = bh / HEADS_;
  int t = threadIdx.x, lane = t & 63, wv = t >> 6;
  int l15 = lane & 15, lhi = lane >> 4;
  const unsigned short* base = qkv + (size_t)bl*K_*(3*C_) + h*HD_;
  __shared__ unsigned short Ql[64][72];
  __shared__ unsigned short Kl[64][72];
  __shared__ unsigned short Vt[64][72];   // [d][k]
  __shared__ unsigned short Pl[4][16][72];
  // stage Q (64 rows x 64 d)
  {
    int r = t >> 2, d0 = (t & 3) * 16;
    const uint4* src = reinterpret_cast<const uint4*>(base + (size_t)(q0+r)*(3*C_) + d0);
    *reinterpret_cast<uint4*>(&Ql[r][d0])   = src[0];
    *reinterpret_cast<uint4*>(&Ql[r][d0+8]) = src[1];
  }
  __syncthreads();
  float m_st[4] = {-1e30f,-1e30f,-1e30f,-1e30f};
  float l_st[4] = {0.f,0.f,0.f,0.f};
  f32x4 o[4] = {};
  for (int kt0 = 0; kt0 < K_; kt0 += 64){
    // stage K (64k x 64d) and Vt (64d x 64k)
    {
      int r = t >> 2, d0 = (t & 3) * 16;
      const uint4* src = reinterpret_cast<const uint4*>(base + (size_t)(kt0+r)*(3*C_) + C_ + d0);
      *reinterpret_cast<uint4*>(&Kl[r][d0])   = src[0];
      *reinterpret_cast<uint4*>(&Kl[r][d0+8]) = src[1];
      int kp = t & 31, vd0 = (t >> 5) * 8, k = 2*kp;
      const ushort4* v0 = reinterpret_cast<const ushort4*>(base + (size_t)(kt0+k)*(3*C_)   + 2*C_ + vd0);
      const ushort4* v1 = reinterpret_cast<const ushort4*>(base + (size_t)(kt0+k+1)*(3*C_) + 2*C_ + vd0);
      ushort4 a0 = v0[0], a1 = v0[1], b0 = v1[0], b1 = v1[1];
      unsigned short va[8] = {a0.x,a0.y,a0.z,a0.w,a1.x,a1.y,a1.z,a1.w};
      unsigned short vb[8] = {b0.x,b0.y,b0.z,b0.w,b1.x,b1.y,b1.z,b1.w};
#pragma unroll
      for (int j = 0; j < 8; ++j){
        unsigned u = (unsigned)va[j] | ((unsigned)vb[j] << 16);
        *reinterpret_cast<unsigned*>(&Vt[vd0+j][k]) = u;
      }
    }
    __syncthreads();
    // QK^T: S (16q x 64k) per wave
    f32x4 s[4] = {};
#pragma unroll
    for (int kt = 0; kt < 2; ++kt){
      bf16x8 af = *reinterpret_cast<const bf16x8*>(&Ql[wv*16 + l15][kt*32 + lhi*8]);
#pragma unroll
      for (int nt = 0; nt < 4; ++nt){
        bf16x8 bfr = *reinterpret_cast<const bf16x8*>(&Kl[nt*16 + l15][kt*32 + lhi*8]);
        s[nt] = __builtin_amdgcn_mfma_f32_16x16x32_bf16(af, bfr, s[nt], 0,0,0);
      }
    }
    // online softmax, rows = lhi*4+reg, cols spread over 4 ntiles x 16 lanes
    float corr[4];
#pragma unroll
    for (int reg = 0; reg < 4; ++reg){
      float a0 = s[0][reg]*0.125f, a1 = s[1][reg]*0.125f;
      float a2 = s[2][reg]*0.125f, a3 = s[3][reg]*0.125f;
      float mx = fmaxf(fmaxf(a0,a1), fmaxf(a2,a3));
      mx = fmaxf(mx, __shfl_xor(mx, 1));
      mx = fmaxf(mx, __shfl_xor(mx, 2));
      mx = fmaxf(mx, __shfl_xor(mx, 4));
      mx = fmaxf(mx, __shfl_xor(mx, 8));
      float mn = fmaxf(m_st[reg], mx);
      float c  = __expf(m_st[reg] - mn);
      float p0 = __expf(a0 - mn), p1 = __expf(a1 - mn);
      float p2 = __expf(a2 - mn), p3 = __expf(a3 - mn);
      float ls = p0 + p1 + p2 + p3;
      ls += __shfl_xor(ls, 1);
      ls += __shfl_xor(ls, 2);
      ls += __shfl_xor(ls, 4);
      ls += __shfl_xor(ls, 8);
      l_st[reg] = l_st[reg]*c + ls;
      m_st[reg] = mn; corr[reg] = c;
      int row = lhi*4 + reg;
      Pl[wv][row][       l15] = f2bf(p0);
      Pl[wv][row][16  +  l15] = f2bf(p1);
      Pl[wv][row][32  +  l15] = f2bf(p2);
      Pl[wv][row][48  +  l15] = f2bf(p3);
    }
    __threadfence_block();   // order ds_writes (P) before cross-lane ds_reads
#pragma unroll
    for (int nt = 0; nt < 4; ++nt)
#pragma unroll
      for (int reg = 0; reg < 4; ++reg)
        o[nt][reg] *= corr[reg];
    // PV: O (16q x 64d) += P (16x64) * V (64x64)
#pragma unroll
    for (int kt = 0; kt < 2; ++kt){
      bf16x8 pa = *reinterpret_cast<const bf16x8*>(&Pl[wv][l15][kt*32 + lhi*8]);
#pragma unroll
      for (int nt = 0; nt < 4; ++nt){
        bf16x8 vb = *reinterpret_cast<const bf16x8*>(&Vt[nt*16 + l15][kt*32 + lhi*8]);
        o[nt] = __builtin_amdgcn_mfma_f32_16x16x32_bf16(pa, vb, o[nt], 0,0,0);
      }
    }
    __syncthreads();
  }
#pragma unroll
  for (int reg = 0; reg < 4; ++reg){
    float inv = 1.f / l_st[reg];
    int q = q0 + wv*16 + lhi*4 + reg;
#pragma unroll
    for (int nt = 0; nt < 4; ++nt)
      ao[((size_t)bl*K_ + q)*C_ + h*HD_ + nt*16 + l15] = f2bf(o[nt][reg]*inv);
  }
}

// ---------------- proj MFMA GEMM + scatter into y (fp32) ----------------
__global__ __launch_bounds__(256) void k_proj(const unsigned short* __restrict__ ain,
    const unsigned* __restrict__ idx, const float* __restrict__ pw,
    const float* __restrict__ pb, float* __restrict__ y, int b_off){
  const int MT = K_/128, NT = C_/64;   // 16, 3
  int bid = blockIdx.x;
  int bl  = bid / (MT*NT);
  int rem = bid % (MT*NT);
  int m0  = (rem / NT) * 128;
  int n0  = (rem % NT) * 64;
  int t = threadIdx.x, lane = t & 63;
  int wv = t >> 6, wm = wv & 1, wn = wv >> 1;
  __shared__ unsigned short Al[128][40];
  __shared__ unsigned short Bl[64][40];
  __shared__ int rows[128];
  if (t < 128) rows[t] = load_idx(idx, (b_off+bl)*K_ + m0 + t);
  __syncthreads();
  f32x4 acc[4][2] = {};
  int l15 = lane & 15, lhi = lane >> 4;
  for (int k0 = 0; k0 < C_; k0 += 32){
    {
      int m = t >> 1;
      const unsigned short* src = ain + ((size_t)bl*K_ + m0 + m)*C_ + k0;
#pragma unroll
      for (int i = 0; i < 4; ++i){
        int kq = (t & 1) + 2*i;
        *reinterpret_cast<ushort4*>(&Al[m][4*kq]) =
            *reinterpret_cast<const ushort4*>(src + 4*kq);
      }
      int n = t >> 2;
      const float* bsrc = pw + (size_t)(n0+n)*C_ + k0;
#pragma unroll
      for (int i = 0; i < 2; ++i){
        int q = (t & 3) + 4*i;
        float4 v = *reinterpret_cast<const float4*>(bsrc + 4*q);
        ushort4 p; p.x=f2bf(v.x); p.y=f2bf(v.y); p.z=f2bf(v.z); p.w=f2bf(v.w);
        *reinterpret_cast<ushort4*>(&Bl[n][4*q]) = p;
      }
    }
    __syncthreads();
    bf16x8 af[4], bfr[2];
#pragma unroll
    for (int mf = 0; mf < 4; ++mf)
      af[mf] = *reinterpret_cast<const bf16x8*>(&Al[wm*64 + mf*16 + l15][lhi*8]);
#pragma unroll
    for (int nf = 0; nf < 2; ++nf)
      bfr[nf] = *reinterpret_cast<const bf16x8*>(&Bl[wn*32 + nf*16 + l15][lhi*8]);
#pragma unroll
    for (int mf = 0; mf < 4; ++mf)
#pragma unroll
      for (int nf = 0; nf < 2; ++nf)
        acc[mf][nf] = __builtin_amdgcn_mfma_f32_16x16x32_bf16(af[mf], bfr[nf], acc[mf][nf], 0,0,0);
    __syncthreads();
  }
#pragma unroll
  for (int mf = 0; mf < 4; ++mf){
    int mb = wm*64 + mf*16 + lhi*4;
#pragma unroll
    for (int nf = 0; nf < 2; ++nf){
      int n = n0 + wn*32 + nf*16 + l15;
      float bv = pb[n];
#pragma unroll
      for (int r = 0; r < 4; ++r)
        y[((size_t)bl*N_ + rows[mb + r])*C_ + n] = acc[mf][nf][r] + bv;
    }
  }
}

// ---------------- residual + LN2: -> ln2t (B,C,N)  [ln2t == d_out] ----------------
__global__ __launch_bounds__(64) void k_ln2(const float* __restrict__ x,
    const float* __restrict__ y, const float* __restrict__ w,
    const float* __restrict__ bias, float* __restrict__ ln2t, int b_off){
  int blk = blockIdx.x;
  int bl = blk / (N_/64);
  int b  = b_off + bl;
  int n0 = (blk % (N_/64)) * 64;
  int t  = threadIdx.x;
  __shared__ float tile[64][C_+1];
  const float* yb = y + ((size_t)bl*N_ + n0)*C_;
  for (int i = 0; i < C_; ++i){
    int li = t + 64*i;
    tile[li/C_][li%C_] = yb[li];
  }
  __syncthreads();
  const float* xb = x + (size_t)b*C_*N_ + n0;
  float sum = 0.f, sq = 0.f;
  for (int c = 0; c < C_; ++c){
    float v = xb[(size_t)c*N_ + t] + tile[t][c];
    tile[t][c] = v;
    sum += v; sq += v*v;
  }
  float mu = sum * (1.f/C_);
  float rstd = rsqrtf(sq*(1.f/C_) - mu*mu + 1e-5f);
  for (int c = 0; c < C_; ++c)
    tile[t][c] = (tile[t][c]-mu)*rstd*w[c] + bias[c];
  __syncthreads();
  float* ob = ln2t + (size_t)b*C_*N_ + n0;
  for (int c = 0; c < C_; ++c)
    ob[(size_t)c*N_ + t] = tile[t][c];
}

// ---------------- fc1 MFMA (one batch): ln2t (C,N) fp32 -> h1 bf16 (HID,N) ----------------
__global__ __launch_bounds__(256) void k_fc1(const float* __restrict__ a,
    const float* __restrict__ wgt, const float* __restrict__ bias,
    unsigned short* __restrict__ h1){
  const int NT = HID_/64;             // 12
  int bid = blockIdx.x;
  int m0  = (bid / NT) * 128;
  int n0  = (bid % NT) * 64;
  int t = threadIdx.x, lane = t & 63;
  int wv = t >> 6, wm = wv & 1, wn = wv >> 1;
  __shared__ unsigned short Al[128][40];
  __shared__ unsigned short Bl[64][40];
  f32x4 acc[4][2] = {};
  int l15 = lane & 15, lhi = lane >> 4;
  for (int k0 = 0; k0 < C_; k0 += 32){
    {
      int m = t & 127;
      const float* src = a + (size_t)k0*N_ + m0 + m;
#pragma unroll
      for (int i = 0; i < 8; ++i){
        int pi = (t >> 7) + 2*i;       // 0..15
        float v0 = src[(size_t)(2*pi)*N_];
        float v1 = src[(size_t)(2*pi+1)*N_];
        unsigned u = (unsigned)f2bf(v0) | ((unsigned)f2bf(v1) << 16);
        *reinterpret_cast<unsigned*>(&Al[m][2*pi]) = u;
      }
      int n = t >> 2;
      const float* bsrc = wgt + (size_t)(n0+n)*C_ + k0;
#pragma unroll
      for (int i = 0; i < 2; ++i){
        int q = (t & 3) + 4*i;
        float4 v = *reinterpret_cast<const float4*>(bsrc + 4*q);
        ushort4 p; p.x=f2bf(v.x); p.y=f2bf(v.y); p.z=f2bf(v.z); p.w=f2bf(v.w);
        *reinterpret_cast<ushort4*>(&Bl[n][4*q]) = p;
      }
    }
    __syncthreads();
    bf16x8 af[4], bfr[2];
#pragma unroll
    for (int mf = 0; mf < 4; ++mf)
      af[mf] = *reinterpret_cast<const bf16x8*>(&Al[wm*64 + mf*16 + l15][lhi*8]);
#pragma unroll
    for (int nf = 0; nf < 2; ++nf)
      bfr[nf] = *reinterpret_cast<const bf16x8*>(&Bl[wn*32 + nf*16 + l15][lhi*8]);
#pragma unroll
    for (int mf = 0; mf < 4; ++mf)
#pragma unroll
      for (int nf = 0; nf < 2; ++nf)
        acc[mf][nf] = __builtin_amdgcn_mfma_f32_16x16x32_bf16(af[mf], bfr[nf], acc[mf][nf], 0,0,0);
    __syncthreads();
  }
#pragma unroll
  for (int mf = 0; mf < 4; ++mf){
    int mb = m0 + wm*64 + mf*16 + lhi*4;
#pragma unroll
    for (int nf = 0; nf < 2; ++nf){
      int n = n0 + wn*32 + nf*16 + l15;
      float bv = bias[n];
      ushort4 pk;
      pk.x = f2bf(acc[mf][nf][0] + bv);
      pk.y = f2bf(acc[mf][nf][1] + bv);
      pk.z = f2bf(acc[mf][nf][2] + bv);
      pk.w = f2bf(acc[mf][nf][3] + bv);
      *reinterpret_cast<ushort4*>(&h1[(size_t)n*N_ + mb]) = pk;
    }
  }
}

// ---------------- depthwise 3x3 + exact GELU (one batch) ----------------
__global__ __launch_bounds__(256) void k_conv(const unsigned short* __restrict__ h1,
    const float* __restrict__ dw, unsigned short* __restrict__ g){
  size_t gid = (size_t)blockIdx.x*256 + threadIdx.x;
  int ww = (int)(gid % W_);
  int hh = (int)((gid / W_) % H_);
  int ch = (int)(gid / N_);
  const unsigned short* plane = h1 + (size_t)ch*N_;
  const float* wv = dw + (size_t)ch*9;
  float s = 0.f;
#pragma unroll
  for (int ky = 0; ky < 3; ++ky){
    int yy = hh + ky - 1;
    if (yy < 0 || yy >= H_) continue;
#pragma unroll
    for (int kx = 0; kx < 3; ++kx){
      int xx = ww + kx - 1;
      if (xx < 0 || xx >= W_) continue;
      s += bf2f(plane[yy*W_ + xx]) * wv[ky*3+kx];
    }
  }
  float ge = 0.5f*s*(1.f + erff(s*0.70710678f));
  g[gid] = f2bf(ge);
}

// ---------------- fc2 MFMA + bias + residual (one batch), io = out[b] (C,N) ----------------
__global__ __launch_bounds__(256) void k_fc2(const unsigned short* __restrict__ g,
    const float* __restrict__ wgt, const float* __restrict__ bias,
    float* io){
  const int NT = C_/64;               // 3
  int bid = blockIdx.x;
  int m0  = (bid / NT) * 128;
  int n0  = (bid % NT) * 64;
  int t = threadIdx.x, lane = t & 63;
  int wv = t >> 6, wm = wv & 1, wn = wv >> 1;
  __shared__ unsigned short Al[128][40];
  __shared__ unsigned short Bl[64][40];
  f32x4 acc[4][2] = {};
  int l15 = lane & 15, lhi = lane >> 4;
  for (int k0 = 0; k0 < HID_; k0 += 32){
    {
      int m = t & 127;
      const unsigned short* src = g + (size_t)k0*N_ + m0 + m;
#pragma unroll
      for (int i = 0; i < 8; ++i){
        int pi = (t >> 7) + 2*i;
        unsigned short v0 = src[(size_t)(2*pi)*N_];
        unsigned short v1 = src[(size_t)(2*pi+1)*N_];
        unsigned u = (unsigned)v0 | ((unsigned)v1 << 16);
        *reinterpret_cast<unsigned*>(&Al[m][2*pi]) = u;
      }
      int n = t >> 2;
      const float* bsrc = wgt + (size_t)(n0+n)*HID_ + k0;
#pragma unroll
      for (int i = 0; i < 2; ++i){
        int q = (t & 3) + 4*i;
        float4 v = *reinterpret_cast<const float4*>(bsrc + 4*q);
        ushort4 p; p.x=f2bf(v.x); p.y=f2bf(v.y); p.z=f2bf(v.z); p.w=f2bf(v.w);
        *reinterpret_cast<ushort4*>(&Bl[n][4*q]) = p;
      }
    }
    __syncthreads();
    bf16x8 af[4], bfr[2];
#pragma unroll
    for (int mf = 0; mf < 4; ++mf)
      af[mf] = *reinterpret_cast<const bf16x8*>(&Al[wm*64 + mf*16 + l15][lhi*8]);
#pragma unroll
    for (int nf = 0; nf < 2; ++nf)
      bfr[nf] = *reinterpret_cast<const bf16x8*>(&Bl[wn*32 + nf*16 + l15][lhi*8]);
#pragma unroll
    for (int mf = 0; mf < 4; ++mf)
#pragma unroll
      for (int nf = 0; nf < 2; ++nf)
        acc[mf][nf] = __builtin_amdgcn_mfma_f32_16x16x32_bf16(af[mf], bfr[nf], acc[mf][nf], 0,0,0);
    __syncthreads();
  }
#pragma unroll
  for (int mf = 0; mf < 4; ++mf){
    int mb = m0 + wm*64 + mf*16 + lhi*4;
#pragma unroll
    for (int nf = 0; nf < 2; ++nf){
      int c = n0 + wn*32 + nf*16 + l15;
      float bv = bias[c];
      size_t off = (size_t)c*N_ + mb;
      float4 rr = *reinterpret_cast<const float4*>(io + off);
      float4 v = make_float4(rr.x + acc[mf][nf][0] + bv, rr.y + acc[mf][nf][1] + bv,
                             rr.z + acc[mf][nf][2] + bv, rr.w + acc[mf][nf][3] + bv);
      *reinterpret_cast<float4*>(io + off) = v;
    }
  }
}

extern "C" void kernel_launch(void* const* d_in, const int* in_sizes, int n_in,
                              void* d_out, int out_size, void* d_ws, size_t ws_size,
                              hipStream_t stream) {
  const float*    x      = (const float*)d_in[0];
  const unsigned* idx    = (const unsigned*)d_in[1];
  const float*    ln1_w  = (const float*)d_in[2];
  const float*    ln1_b  = (const float*)d_in[3];
  const float*    qkv_w  = (const float*)d_in[4];
  const float*    proj_w = (const float*)d_in[5];
  const float*    proj_b = (const float*)d_in[6];
  const float*    ln2_w  = (const float*)d_in[7];
  const float*    ln2_b  = (const float*)d_in[8];
  const float*    fc1_w  = (const float*)d_in[9];
  const float*    fc1_b  = (const float*)d_in[10];
  const float*    dw_w   = (const float*)d_in[11];
  const float*    fc2_w  = (const float*)d_in[12];
  const float*    fc2_b  = (const float*)d_in[13];
  float* out = (float*)d_out;          // doubles as ln2t (B,C,N) f32

  const size_t SZ_H1 = (size_t)HID_*N_*2;                 // 25.2 MB per batch
  auto need = [&](int nb)->size_t{
    size_t szY = (size_t)nb*N_*C_*4;
    size_t szQ = (size_t)nb*K_*3*C_*2;
    size_t szA = (size_t)nb*K_*C_*2;
    size_t tail = szQ + szA; if (tail < 2*SZ_H1) tail = 2*SZ_H1;
    return szY + tail;
  };
  int nb = (ws_size >= need(B_)) ? B_ : 1;   // deterministic: ws_size is fixed

  char* ws = (char*)d_ws;
  size_t szY = (size_t)nb*N_*C_*4;
  size_t szQ = (size_t)nb*K_*3*C_*2;
  float*          y    = (float*)ws;
  unsigned short* qkvb = (unsigned short*)(ws + szY);
  unsigned short* aob  = (unsigned short*)(ws + szY + szQ);
  // h1/g reuse the qkv/ao region (dead by the time fc1 runs)
  unsigned short* h1 = (unsigned short*)(ws + szY);
  unsigned short* gg = h1 + (size_t)HID_*N_;

  for (int b0 = 0; b0 < B_; b0 += nb){
    k_ln1 <<<nb*(N_/64),                      64, 0, stream>>>(x, ln1_w, ln1_b, y, b0);
    k_qkv <<<nb*(K_/128)*((3*C_)/64),        256, 0, stream>>>(y, idx, qkv_w, qkvb, b0);
    k_attn<<<nb*HEADS_*(K_/64),              256, 0, stream>>>(qkvb, aob);
    k_proj<<<nb*(K_/128)*(C_/64),            256, 0, stream>>>(aob, idx, proj_w, proj_b, y, b0);
    k_ln2 <<<nb*(N_/64),                      64, 0, stream>>>(x, y, ln2_w, ln2_b, out, b0);
    for (int b = b0; b < b0 + nb; ++b){
      const float* ln2b = out + (size_t)b*C_*N_;
      k_fc1 <<<(N_/128)*(HID_/64), 256, 0, stream>>>(ln2b, fc1_w, fc1_b, h1);
      k_conv<<<(int)(((size_t)HID_*N_)/256), 256, 0, stream>>>(h1, dw_w, gg);
      k_fc2 <<<(N_/128)*(C_/64),   256, 0, stream>>>(gg, fc2_w, fc2_b,
                                                     (float*)(out + (size_t)b*C_*N_));
    }
  }
}

// Round 4
// 446.822 us; speedup vs baseline: 3.6936x; 1.6525x over previous
//
#include <hip/hip_runtime.h>

#define B_ 4
#define C_ 192
#define H_ 128
#define W_ 128
#define N_ (H_*W_)      // 16384
#define K_ 2048
#define HEADS_ 3
#define HD_ 64
#define HID_ 768
#define NC_ 4           // attention split-K chunks
#define KC_ (K_/NC_)    // 512

typedef __attribute__((ext_vector_type(4))) float f32x4;
typedef __attribute__((ext_vector_type(8))) short bf16x8;

__device__ __forceinline__ unsigned short f2bf(float f){
  unsigned int u = __float_as_uint(f);
  u += 0x7FFFu + ((u >> 16) & 1u);
  return (unsigned short)(u >> 16);
}
__device__ __forceinline__ float bf2f(unsigned short s){
  return __uint_as_float(((unsigned int)s) << 16);
}

// indices may arrive as int32 or int64. Sorted-unique ascending indices =>
// u32 words 1,3,5,7 are nonzero iff storage is int32 (int64 high words are 0).
__device__ __forceinline__ int load_idx(const unsigned* __restrict__ ip, int pos){
  bool is64 = (ip[1]==0u) & (ip[3]==0u) & (ip[5]==0u) & (ip[7]==0u);
  int v = is64 ? (int)ip[2*pos] : (int)ip[pos];
  return min(max(v, 0), N_-1);
}

// ---------------- LN1: x (B,C,N) -> y (nb,N,C) fp32 ----------------
__global__ __launch_bounds__(64) void k_ln1(const float* __restrict__ x,
    const float* __restrict__ w, const float* __restrict__ bias,
    float* __restrict__ y, int b_off){
  int blk = blockIdx.x;
  int bl = blk / (N_/64);
  int b  = b_off + bl;
  int n0 = (blk % (N_/64)) * 64;
  int t  = threadIdx.x;
  __shared__ float tile[64][C_+1];
  const float* xb = x + (size_t)b*C_*N_ + n0;
  float sum = 0.f, sq = 0.f;
  for (int c = 0; c < C_; ++c){
    float v = xb[(size_t)c*N_ + t];
    tile[t][c] = v;
    sum += v; sq += v*v;
  }
  float mu = sum * (1.f/C_);
  float rstd = rsqrtf(sq*(1.f/C_) - mu*mu + 1e-5f);
  for (int c = 0; c < C_; ++c)
    tile[t][c] = (tile[t][c]-mu)*rstd*w[c] + bias[c];
  __syncthreads();
  float* yb = y + ((size_t)bl*N_ + n0)*C_;
  for (int tok = 0; tok < 64; ++tok){
#pragma unroll
    for (int j = 0; j < 3; ++j)
      yb[tok*C_ + j*64 + t] = tile[tok][j*64 + t];
  }
}

// ---------------- QKV MFMA GEMM with gather: y fp32 -> qkv bf16 (bl,K,576) ----------------
__global__ __launch_bounds__(256) void k_qkv(const float* __restrict__ y,
    const unsigned* __restrict__ idx, const float* __restrict__ wq,
    unsigned short* __restrict__ qkv, int b_off){
  const int NT = (3*C_)/64;  // 9
  int bid = blockIdx.x;
  int bl  = bid / (16*NT);
  int rem = bid % (16*NT);
  int m0  = (rem / NT) * 128;
  int n0  = (rem % NT) * 64;
  int t = threadIdx.x, lane = t & 63;
  int wv = t >> 6, wm = wv & 1, wn = wv >> 1;
  __shared__ unsigned short Al[128][40];
  __shared__ unsigned short Bl[64][40];
  __shared__ int rows[128];
  if (t < 128) rows[t] = load_idx(idx, (b_off+bl)*K_ + m0 + t);
  __syncthreads();
  f32x4 acc[4][2] = {};
  int l15 = lane & 15, lhi = lane >> 4;
  for (int k0 = 0; k0 < C_; k0 += 32){
    {
      int m = t >> 1;
      const float* src = y + ((size_t)bl*N_ + rows[m])*C_ + k0;
#pragma unroll
      for (int i = 0; i < 4; ++i){
        int kq = (t & 1) + 2*i;
        float4 v = *reinterpret_cast<const float4*>(src + 4*kq);
        ushort4 p; p.x=f2bf(v.x); p.y=f2bf(v.y); p.z=f2bf(v.z); p.w=f2bf(v.w);
        *reinterpret_cast<ushort4*>(&Al[m][4*kq]) = p;
      }
      int n = t >> 2;
      const float* bsrc = wq + (size_t)(n0+n)*C_ + k0;
#pragma unroll
      for (int i = 0; i < 2; ++i){
        int q = (t & 3) + 4*i;
        float4 v = *reinterpret_cast<const float4*>(bsrc + 4*q);
        ushort4 p; p.x=f2bf(v.x); p.y=f2bf(v.y); p.z=f2bf(v.z); p.w=f2bf(v.w);
        *reinterpret_cast<ushort4*>(&Bl[n][4*q]) = p;
      }
    }
    __syncthreads();
    bf16x8 af[4], bfr[2];
#pragma unroll
    for (int mf = 0; mf < 4; ++mf)
      af[mf] = *reinterpret_cast<const bf16x8*>(&Al[wm*64 + mf*16 + l15][lhi*8]);
#pragma unroll
    for (int nf = 0; nf < 2; ++nf)
      bfr[nf] = *reinterpret_cast<const bf16x8*>(&Bl[wn*32 + nf*16 + l15][lhi*8]);
#pragma unroll
    for (int mf = 0; mf < 4; ++mf)
#pragma unroll
      for (int nf = 0; nf < 2; ++nf)
        acc[mf][nf] = __builtin_amdgcn_mfma_f32_16x16x32_bf16(af[mf], bfr[nf], acc[mf][nf], 0,0,0);
    __syncthreads();
  }
#pragma unroll
  for (int mf = 0; mf < 4; ++mf){
    int mb = m0 + wm*64 + mf*16 + lhi*4;
#pragma unroll
    for (int nf = 0; nf < 2; ++nf){
      int n = n0 + wn*32 + nf*16 + l15;
#pragma unroll
      for (int r = 0; r < 4; ++r)
        qkv[((size_t)bl*K_ + mb + r)*(3*C_) + n] = f2bf(acc[mf][nf][r]);
    }
  }
}

// ------- attention split-K: block=(bl,h,64 q rows, chunk c), 4 waves -------
__global__ __launch_bounds__(256) void k_attn(const unsigned short* __restrict__ qkv,
    float* __restrict__ po, float* __restrict__ pml, int nb){
  int bid = blockIdx.x;
  int c   = bid & (NC_-1);
  int qt  = (bid >> 2) & 31;
  int bh  = bid >> 7;
  int h = bh % HEADS_, bl = bh / HEADS_;
  int q0 = qt*64;
  int t = threadIdx.x, lane = t & 63, wv = t >> 6;
  int l15 = lane & 15, lhi = lane >> 4;
  const unsigned short* base = qkv + (size_t)bl*K_*(3*C_) + h*HD_;
  __shared__ unsigned short Ql[64][72];
  __shared__ unsigned short Kl[64][72];
  __shared__ unsigned short Vt[64][72];   // [d][k]
  __shared__ unsigned short Pl[4][16][72];
  // stage Q (64 rows x 64 d)
  {
    int r = t >> 2, d0 = (t & 3) * 16;
    const uint4* src = reinterpret_cast<const uint4*>(base + (size_t)(q0+r)*(3*C_) + d0);
    *reinterpret_cast<uint4*>(&Ql[r][d0])   = src[0];
    *reinterpret_cast<uint4*>(&Ql[r][d0+8]) = src[1];
  }
  __syncthreads();
  float m_st[4] = {-1e30f,-1e30f,-1e30f,-1e30f};
  float l_st[4] = {0.f,0.f,0.f,0.f};
  f32x4 o[4] = {};
  for (int kt0 = c*KC_; kt0 < c*KC_ + KC_; kt0 += 64){
    // stage K (64k x 64d) and Vt (64d x 64k)
    {
      int r = t >> 2, d0 = (t & 3) * 16;
      const uint4* src = reinterpret_cast<const uint4*>(base + (size_t)(kt0+r)*(3*C_) + C_ + d0);
      *reinterpret_cast<uint4*>(&Kl[r][d0])   = src[0];
      *reinterpret_cast<uint4*>(&Kl[r][d0+8]) = src[1];
      int kp = t & 31, vd0 = (t >> 5) * 8, k = 2*kp;
      const ushort4* v0 = reinterpret_cast<const ushort4*>(base + (size_t)(kt0+k)*(3*C_)   + 2*C_ + vd0);
      const ushort4* v1 = reinterpret_cast<const ushort4*>(base + (size_t)(kt0+k+1)*(3*C_) + 2*C_ + vd0);
      ushort4 a0 = v0[0], a1 = v0[1], b0 = v1[0], b1 = v1[1];
      unsigned short va[8] = {a0.x,a0.y,a0.z,a0.w,a1.x,a1.y,a1.z,a1.w};
      unsigned short vb[8] = {b0.x,b0.y,b0.z,b0.w,b1.x,b1.y,b1.z,b1.w};
#pragma unroll
      for (int j = 0; j < 8; ++j){
        unsigned u = (unsigned)va[j] | ((unsigned)vb[j] << 16);
        *reinterpret_cast<unsigned*>(&Vt[vd0+j][k]) = u;
      }
    }
    __syncthreads();
    // QK^T: S (16q x 64k) per wave
    f32x4 s[4] = {};
#pragma unroll
    for (int kt = 0; kt < 2; ++kt){
      bf16x8 af = *reinterpret_cast<const bf16x8*>(&Ql[wv*16 + l15][kt*32 + lhi*8]);
#pragma unroll
      for (int nt = 0; nt < 4; ++nt){
        bf16x8 bfr = *reinterpret_cast<const bf16x8*>(&Kl[nt*16 + l15][kt*32 + lhi*8]);
        s[nt] = __builtin_amdgcn_mfma_f32_16x16x32_bf16(af, bfr, s[nt], 0,0,0);
      }
    }
    // online softmax; P written as lane-paired b32 (2-way banks instead of ~8)
    float corr[4];
#pragma unroll
    for (int reg = 0; reg < 4; ++reg){
      float a0 = s[0][reg]*0.125f, a1 = s[1][reg]*0.125f;
      float a2 = s[2][reg]*0.125f, a3 = s[3][reg]*0.125f;
      float mx = fmaxf(fmaxf(a0,a1), fmaxf(a2,a3));
      mx = fmaxf(mx, __shfl_xor(mx, 1));
      mx = fmaxf(mx, __shfl_xor(mx, 2));
      mx = fmaxf(mx, __shfl_xor(mx, 4));
      mx = fmaxf(mx, __shfl_xor(mx, 8));
      float mn = fmaxf(m_st[reg], mx);
      float cr = __expf(m_st[reg] - mn);
      float p0 = __expf(a0 - mn), p1 = __expf(a1 - mn);
      float p2 = __expf(a2 - mn), p3 = __expf(a3 - mn);
      float ls = p0 + p1 + p2 + p3;
      ls += __shfl_xor(ls, 1);
      ls += __shfl_xor(ls, 2);
      ls += __shfl_xor(ls, 4);
      ls += __shfl_xor(ls, 8);
      l_st[reg] = l_st[reg]*cr + ls;
      m_st[reg] = mn; corr[reg] = cr;
      int row = lhi*4 + reg;
      float q0v = __shfl_xor(p0, 1), q1v = __shfl_xor(p1, 1);
      float q2v = __shfl_xor(p2, 1), q3v = __shfl_xor(p3, 1);
      int e = l15 & ~1;
      unsigned uA, uB; int cA, cB;
      if (!(l15 & 1)){
        uA = (unsigned)f2bf(p0) | ((unsigned)f2bf(q0v) << 16); cA = e;
        uB = (unsigned)f2bf(p2) | ((unsigned)f2bf(q2v) << 16); cB = 32 + e;
      } else {
        uA = (unsigned)f2bf(q1v) | ((unsigned)f2bf(p1) << 16); cA = 16 + e;
        uB = (unsigned)f2bf(q3v) | ((unsigned)f2bf(p3) << 16); cB = 48 + e;
      }
      *reinterpret_cast<unsigned*>(&Pl[wv][row][cA]) = uA;
      *reinterpret_cast<unsigned*>(&Pl[wv][row][cB]) = uB;
    }
    __threadfence_block();   // order P ds_writes before same-wave ds_reads
#pragma unroll
    for (int nt = 0; nt < 4; ++nt)
#pragma unroll
      for (int reg = 0; reg < 4; ++reg)
        o[nt][reg] *= corr[reg];
    // PV: O (16q x 64d) += P (16x64) * V (64x64)
#pragma unroll
    for (int kt = 0; kt < 2; ++kt){
      bf16x8 pa = *reinterpret_cast<const bf16x8*>(&Pl[wv][l15][kt*32 + lhi*8]);
#pragma unroll
      for (int nt = 0; nt < 4; ++nt){
        bf16x8 vb = *reinterpret_cast<const bf16x8*>(&Vt[nt*16 + l15][kt*32 + lhi*8]);
        o[nt] = __builtin_amdgcn_mfma_f32_16x16x32_bf16(pa, vb, o[nt], 0,0,0);
      }
    }
    __syncthreads();
  }
  int R = nb*HEADS_*K_;
  int rowb = (bl*HEADS_ + h)*K_;
#pragma unroll
  for (int reg = 0; reg < 4; ++reg){
    int rq = rowb + q0 + wv*16 + lhi*4 + reg;
#pragma unroll
    for (int nt = 0; nt < 4; ++nt)
      po[((size_t)c*R + rq)*HD_ + nt*16 + l15] = o[nt][reg];
    if (l15 == 0)
      *reinterpret_cast<float2*>(pml + 2*((size_t)c*R + rq)) =
          make_float2(m_st[reg], l_st[reg]);
  }
}

// ---------------- merge split-K partials -> ao bf16 (bl,K,C) ----------------
__global__ __launch_bounds__(256) void k_amerge(const float* __restrict__ po,
    const float* __restrict__ pml, unsigned short* __restrict__ ao, int nb){
  int R = nb*HEADS_*K_;
  int row = blockIdx.x*4 + (threadIdx.x >> 6);
  int lane = threadIdx.x & 63;
  float m[NC_], l[NC_];
#pragma unroll
  for (int cc = 0; cc < NC_; ++cc){
    float2 v = *reinterpret_cast<const float2*>(pml + 2*((size_t)cc*R + row));
    m[cc] = v.x; l[cc] = v.y;
  }
  float M = fmaxf(fmaxf(m[0],m[1]), fmaxf(m[2],m[3]));
  float L = 0.f, o = 0.f;
#pragma unroll
  for (int cc = 0; cc < NC_; ++cc){
    float e = __expf(m[cc] - M);
    L += l[cc]*e;
    o += e * po[((size_t)cc*R + row)*HD_ + lane];
  }
  o /= L;
  int q = row & (K_-1);
  int bh = row >> 11;
  int h = bh % HEADS_, bl = bh / HEADS_;
  ao[((size_t)bl*K_ + q)*C_ + h*HD_ + lane] = f2bf(o);
}

// ---------------- proj MFMA GEMM + scatter into y (fp32) ----------------
__global__ __launch_bounds__(256) void k_proj(const unsigned short* __restrict__ ain,
    const unsigned* __restrict__ idx, const float* __restrict__ pw,
    const float* __restrict__ pb, float* __restrict__ y, int b_off){
  const int NT = C_/64;   // 3
  int bid = blockIdx.x;
  int bl  = bid / (16*NT);
  int rem = bid % (16*NT);
  int m0  = (rem / NT) * 128;
  int n0  = (rem % NT) * 64;
  int t = threadIdx.x, lane = t & 63;
  int wv = t >> 6, wm = wv & 1, wn = wv >> 1;
  __shared__ unsigned short Al[128][40];
  __shared__ unsigned short Bl[64][40];
  __shared__ int rows[128];
  if (t < 128) rows[t] = load_idx(idx, (b_off+bl)*K_ + m0 + t);
  __syncthreads();
  f32x4 acc[4][2] = {};
  int l15 = lane & 15, lhi = lane >> 4;
  for (int k0 = 0; k0 < C_; k0 += 32){
    {
      int m = t >> 1;
      const unsigned short* src = ain + ((size_t)bl*K_ + m0 + m)*C_ + k0;
#pragma unroll
      for (int i = 0; i < 4; ++i){
        int kq = (t & 1) + 2*i;
        *reinterpret_cast<ushort4*>(&Al[m][4*kq]) =
            *reinterpret_cast<const ushort4*>(src + 4*kq);
      }
      int n = t >> 2;
      const float* bsrc = pw + (size_t)(n0+n)*C_ + k0;
#pragma unroll
      for (int i = 0; i < 2; ++i){
        int q = (t & 3) + 4*i;
        float4 v = *reinterpret_cast<const float4*>(bsrc + 4*q);
        ushort4 p; p.x=f2bf(v.x); p.y=f2bf(v.y); p.z=f2bf(v.z); p.w=f2bf(v.w);
        *reinterpret_cast<ushort4*>(&Bl[n][4*q]) = p;
      }
    }
    __syncthreads();
    bf16x8 af[4], bfr[2];
#pragma unroll
    for (int mf = 0; mf < 4; ++mf)
      af[mf] = *reinterpret_cast<const bf16x8*>(&Al[wm*64 + mf*16 + l15][lhi*8]);
#pragma unroll
    for (int nf = 0; nf < 2; ++nf)
      bfr[nf] = *reinterpret_cast<const bf16x8*>(&Bl[wn*32 + nf*16 + l15][lhi*8]);
#pragma unroll
    for (int mf = 0; mf < 4; ++mf)
#pragma unroll
      for (int nf = 0; nf < 2; ++nf)
        acc[mf][nf] = __builtin_amdgcn_mfma_f32_16x16x32_bf16(af[mf], bfr[nf], acc[mf][nf], 0,0,0);
    __syncthreads();
  }
#pragma unroll
  for (int mf = 0; mf < 4; ++mf){
    int mb = wm*64 + mf*16 + lhi*4;
#pragma unroll
    for (int nf = 0; nf < 2; ++nf){
      int n = n0 + wn*32 + nf*16 + l15;
      float bv = pb[n];
#pragma unroll
      for (int r = 0; r < 4; ++r)
        y[((size_t)bl*N_ + rows[mb + r])*C_ + n] = acc[mf][nf][r] + bv;
    }
  }
}

// ---------------- residual + LN2: -> ln2t (B,C,N)  [ln2t == d_out] ----------------
__global__ __launch_bounds__(64) void k_ln2(const float* __restrict__ x,
    const float* __restrict__ y, const float* __restrict__ w,
    const float* __restrict__ bias, float* __restrict__ ln2t, int b_off){
  int blk = blockIdx.x;
  int bl = blk / (N_/64);
  int b  = b_off + bl;
  int n0 = (blk % (N_/64)) * 64;
  int t  = threadIdx.x;
  __shared__ float tile[64][C_+1];
  const float* yb = y + ((size_t)bl*N_ + n0)*C_;
  for (int i = 0; i < C_; ++i){
    int li = t + 64*i;
    tile[li/C_][li%C_] = yb[li];
  }
  __syncthreads();
  const float* xb = x + (size_t)b*C_*N_ + n0;
  float sum = 0.f, sq = 0.f;
  for (int c = 0; c < C_; ++c){
    float v = xb[(size_t)c*N_ + t] + tile[t][c];
    tile[t][c] = v;
    sum += v; sq += v*v;
  }
  float mu = sum * (1.f/C_);
  float rstd = rsqrtf(sq*(1.f/C_) - mu*mu + 1e-5f);
  for (int c = 0; c < C_; ++c)
    tile[t][c] = (tile[t][c]-mu)*rstd*w[c] + bias[c];
  __syncthreads();
  float* ob = ln2t + (size_t)b*C_*N_ + n0;
  for (int c = 0; c < C_; ++c)
    ob[(size_t)c*N_ + t] = tile[t][c];
}

// ------- fc1 MFMA batch-wide: ln2t (b,C,N) fp32 -> h1 bf16 (bl,HID,N) -------
__global__ __launch_bounds__(256) void k_fc1(const float* __restrict__ ln2t,
    const float* __restrict__ wgt, const float* __restrict__ bias,
    unsigned short* __restrict__ h1, int b_off){
  const int NT = HID_/64;             // 12
  int bid = blockIdx.x;
  int bl  = bid / (128*NT);
  int rem = bid % (128*NT);
  int m0  = (rem / NT) * 128;
  int n0  = (rem % NT) * 64;
  int t = threadIdx.x, lane = t & 63;
  int wv = t >> 6, wm = wv & 1, wn = wv >> 1;
  __shared__ unsigned short Al[128][40];
  __shared__ unsigned short Bl[64][40];
  const float* a = ln2t + (size_t)(b_off+bl)*C_*N_;
  unsigned short* hb = h1 + (size_t)bl*HID_*N_;
  f32x4 acc[4][2] = {};
  int l15 = lane & 15, lhi = lane >> 4;
  for (int k0 = 0; k0 < C_; k0 += 32){
    {
      int m = t & 127;
      const float* src = a + (size_t)k0*N_ + m0 + m;
#pragma unroll
      for (int i = 0; i < 8; ++i){
        int pi = (t >> 7) + 2*i;       // 0..15
        float v0 = src[(size_t)(2*pi)*N_];
        float v1 = src[(size_t)(2*pi+1)*N_];
        unsigned u = (unsigned)f2bf(v0) | ((unsigned)f2bf(v1) << 16);
        *reinterpret_cast<unsigned*>(&Al[m][2*pi]) = u;
      }
      int n = t >> 2;
      const float* bsrc = wgt + (size_t)(n0+n)*C_ + k0;
#pragma unroll
      for (int i = 0; i < 2; ++i){
        int q = (t & 3) + 4*i;
        float4 v = *reinterpret_cast<const float4*>(bsrc + 4*q);
        ushort4 p; p.x=f2bf(v.x); p.y=f2bf(v.y); p.z=f2bf(v.z); p.w=f2bf(v.w);
        *reinterpret_cast<ushort4*>(&Bl[n][4*q]) = p;
      }
    }
    __syncthreads();
    bf16x8 af[4], bfr[2];
#pragma unroll
    for (int mf = 0; mf < 4; ++mf)
      af[mf] = *reinterpret_cast<const bf16x8*>(&Al[wm*64 + mf*16 + l15][lhi*8]);
#pragma unroll
    for (int nf = 0; nf < 2; ++nf)
      bfr[nf] = *reinterpret_cast<const bf16x8*>(&Bl[wn*32 + nf*16 + l15][lhi*8]);
#pragma unroll
    for (int mf = 0; mf < 4; ++mf)
#pragma unroll
      for (int nf = 0; nf < 2; ++nf)
        acc[mf][nf] = __builtin_amdgcn_mfma_f32_16x16x32_bf16(af[mf], bfr[nf], acc[mf][nf], 0,0,0);
    __syncthreads();
  }
#pragma unroll
  for (int mf = 0; mf < 4; ++mf){
    int mb = m0 + wm*64 + mf*16 + lhi*4;
#pragma unroll
    for (int nf = 0; nf < 2; ++nf){
      int n = n0 + wn*32 + nf*16 + l15;
      float bv = bias[n];
      ushort4 pk;
      pk.x = f2bf(acc[mf][nf][0] + bv);
      pk.y = f2bf(acc[mf][nf][1] + bv);
      pk.z = f2bf(acc[mf][nf][2] + bv);
      pk.w = f2bf(acc[mf][nf][3] + bv);
      *reinterpret_cast<ushort4*>(&hb[(size_t)n*N_ + mb]) = pk;
    }
  }
}

// ------- fused depthwise3x3+GELU+fc2+residual: h1 -> out (b,C,N) -------
// block: 2 image rows (256 tokens) x full C=192, 512 threads (8 waves)
__global__ __launch_bounds__(512, 1) void k_fc2f(const unsigned short* __restrict__ h1,
    const float* __restrict__ dw, const float* __restrict__ wgt,
    const float* __restrict__ bias, float* __restrict__ out, int b_off){
  int bid = blockIdx.x;
  int r2  = bid & 63;               // 2-row tile index
  int bl  = bid >> 6;
  int b   = b_off + bl;
  int r0  = r2*2;                   // first image row
  int m0  = r0*W_;                  // token base (256 tokens)
  int t = threadIdx.x, lane = t & 63, wv = t >> 6;
  int wm = wv & 3, wn = wv >> 2;
  int l15 = lane & 15, lhi = lane >> 4;
  __shared__ unsigned short Hs[4*32*128];          // [hrow][ch][cc], xor-swizzled
  __shared__ unsigned char  Alr[256*96 + 64];      // [col][ch] bf16, staggered
  __shared__ unsigned short Bl[192][40];
  const unsigned short* h1b = h1 + (size_t)bl*HID_*N_;
  f32x4 acc[4][6] = {};
  for (int k0 = 0; k0 < HID_; k0 += 32){
    // ---- stage Hs: image rows r0-1 .. r0+2, 32 channels ----
#pragma unroll
    for (int i = 0; i < 4; ++i){
      int li = t + 512*i;            // 0..2047
      int hrow = li >> 9;
      int rem = li & 511;
      int ch = rem >> 4, seg = rem & 15;
      int rrow = r0 - 1 + hrow;
      uint4 v = make_uint4(0u,0u,0u,0u);
      if (rrow >= 0 && rrow < H_)
        v = *reinterpret_cast<const uint4*>(h1b + (size_t)(k0+ch)*N_ + rrow*W_ + seg*8);
      int byte = (((hrow*32 + ch)*128 + seg*8) * 2) ^ ((ch & 7) << 4);
      *reinterpret_cast<uint4*>(reinterpret_cast<char*>(Hs) + byte) = v;
    }
    // ---- stage Bl: 192 x 32 of fc2_w ----
#pragma unroll
    for (int i = 0; i < 3; ++i){
      int li = t + 512*i;            // 0..1535
      int row = li >> 3, q = li & 7;
      float4 v = *reinterpret_cast<const float4*>(wgt + (size_t)row*HID_ + k0 + 4*q);
      ushort4 p; p.x=f2bf(v.x); p.y=f2bf(v.y); p.z=f2bf(v.z); p.w=f2bf(v.w);
      *reinterpret_cast<ushort4*>(&Bl[row][4*q]) = p;
    }
    __syncthreads();
    // ---- conv 3x3 + GELU -> Alr ----
    {
      int ch0 = (t & 15) * 2;
      int cs  = t >> 4;              // 0..31
      int lr  = cs >> 4;             // local row 0/1
      int j0  = (cs & 15) * 8;       // col base
      unsigned short gbuf[2][8];
#pragma unroll
      for (int cd = 0; cd < 2; ++cd){
        int ch = ch0 + cd;
        const float* wp = dw + (size_t)(k0+ch)*9;
        float s[8] = {0.f,0.f,0.f,0.f,0.f,0.f,0.f,0.f};
#pragma unroll
        for (int dy = 0; dy < 3; ++dy){
          int hrow = lr + dy;
          float v[10];
#pragma unroll
          for (int o = 0; o < 10; ++o){
            int cc = j0 + o - 1;
            if (cc < 0 || cc >= 128) v[o] = 0.f;
            else {
              int byte = (((hrow*32 + ch)*128 + cc) * 2) ^ ((ch & 7) << 4);
              v[o] = bf2f(*reinterpret_cast<const unsigned short*>(
                  reinterpret_cast<const char*>(Hs) + byte));
            }
          }
          float wa = wp[dy*3], wb = wp[dy*3+1], wc = wp[dy*3+2];
#pragma unroll
          for (int j = 0; j < 8; ++j)
            s[j] += v[j]*wa + v[j+1]*wb + v[j+2]*wc;
        }
#pragma unroll
        for (int j = 0; j < 8; ++j){
          float xx = s[j];
          float ge = 0.5f*xx*(1.f + erff(xx*0.70710678f));
          gbuf[cd][j] = f2bf(ge);
        }
      }
#pragma unroll
      for (int j = 0; j < 8; ++j){
        int col = lr*128 + j0 + j;
        int byte = col*96 + ((col >> 3) & 1)*64 + ch0*2;
        unsigned u = (unsigned)gbuf[0][j] | ((unsigned)gbuf[1][j] << 16);
        *reinterpret_cast<unsigned*>(Alr + byte) = u;
      }
    }
    __syncthreads();
    // ---- fragments + MFMA ----
    bf16x8 af[4], bfr[6];
#pragma unroll
    for (int mf = 0; mf < 4; ++mf){
      int row = wm*64 + mf*16 + l15;
      int byte = row*96 + ((row >> 3) & 1)*64 + lhi*16;
      af[mf] = *reinterpret_cast<const bf16x8*>(Alr + byte);
    }
#pragma unroll
    for (int nf = 0; nf < 6; ++nf)
      bfr[nf] = *reinterpret_cast<const bf16x8*>(&Bl[wn*96 + nf*16 + l15][lhi*8]);
#pragma unroll
    for (int mf = 0; mf < 4; ++mf)
#pragma unroll
      for (int nf = 0; nf < 6; ++nf)
        acc[mf][nf] = __builtin_amdgcn_mfma_f32_16x16x32_bf16(af[mf], bfr[nf], acc[mf][nf], 0,0,0);
    __syncthreads();
  }
  // epilogue: += bias + residual (out holds ln2t)
#pragma unroll
  for (int mf = 0; mf < 4; ++mf){
    int tok = m0 + wm*64 + mf*16 + lhi*4;
#pragma unroll
    for (int nf = 0; nf < 6; ++nf){
      int cch = wn*96 + nf*16 + l15;
      float bv = bias[cch];
      size_t off = ((size_t)b*C_ + cch)*N_ + tok;
      float4 rr = *reinterpret_cast<const float4*>(out + off);
      float4 v = make_float4(rr.x + acc[mf][nf][0] + bv, rr.y + acc[mf][nf][1] + bv,
                             rr.z + acc[mf][nf][2] + bv, rr.w + acc[mf][nf][3] + bv);
      *reinterpret_cast<float4*>(out + off) = v;
    }
  }
}

extern "C" void kernel_launch(void* const* d_in, const int* in_sizes, int n_in,
                              void* d_out, int out_size, void* d_ws, size_t ws_size,
                              hipStream_t stream) {
  const float*    x      = (const float*)d_in[0];
  const unsigned* idx    = (const unsigned*)d_in[1];
  const float*    ln1_w  = (const float*)d_in[2];
  const float*    ln1_b  = (const float*)d_in[3];
  const float*    qkv_w  = (const float*)d_in[4];
  const float*    proj_w = (const float*)d_in[5];
  const float*    proj_b = (const float*)d_in[6];
  const float*    ln2_w  = (const float*)d_in[7];
  const float*    ln2_b  = (const float*)d_in[8];
  const float*    fc1_w  = (const float*)d_in[9];
  const float*    fc1_b  = (const float*)d_in[10];
  const float*    dw_w   = (const float*)d_in[11];
  const float*    fc2_w  = (const float*)d_in[12];
  const float*    fc2_b  = (const float*)d_in[13];
  float* out = (float*)d_out;          // doubles as ln2t (B,C,N) f32

  const size_t SZY = (size_t)N_*C_*4;              // 12.58 MB / batch
  const size_t SZQ = (size_t)K_*3*C_*2;            //  2.36 MB
  const size_t SZA = (size_t)K_*C_*2;              //  0.79 MB
  const size_t SZO = (size_t)NC_*HEADS_*K_*HD_*4;  //  6.29 MB
  const size_t SZM = (size_t)NC_*HEADS_*K_*2*4;    //  0.20 MB
  const size_t SZH = (size_t)HID_*N_*2;            // 25.17 MB
  int nb = (ws_size >= (size_t)B_*SZH) ? B_ : 1;   // deterministic

  char* ws = (char*)d_ws;
  float*          y    = (float*)ws;
  unsigned short* qkvb = (unsigned short*)(ws + (size_t)nb*SZY);
  unsigned short* aob  = (unsigned short*)(ws + (size_t)nb*(SZY+SZQ));
  float*          po   = (float*)(ws + (size_t)nb*(SZY+SZQ+SZA));
  float*          pml  = (float*)(ws + (size_t)nb*(SZY+SZQ+SZA+SZO));
  unsigned short* h1   = (unsigned short*)ws;      // MLP phase (front dead)

  for (int b0 = 0; b0 < B_; b0 += nb){
    k_ln1   <<<nb*(N_/64),          64, 0, stream>>>(x, ln1_w, ln1_b, y, b0);
    k_qkv   <<<nb*16*9,            256, 0, stream>>>(y, idx, qkv_w, qkvb, b0);
    k_attn  <<<nb*HEADS_*32*NC_,   256, 0, stream>>>(qkvb, po, pml, nb);
    k_amerge<<<nb*HEADS_*K_/4,     256, 0, stream>>>(po, pml, aob, nb);
    k_proj  <<<nb*16*3,            256, 0, stream>>>(aob, idx, proj_w, proj_b, y, b0);
    k_ln2   <<<nb*(N_/64),          64, 0, stream>>>(x, y, ln2_w, ln2_b, out, b0);
    k_fc1   <<<nb*128*12,          256, 0, stream>>>(out, fc1_w, fc1_b, h1, b0);
    k_fc2f  <<<nb*64,              512, 0, stream>>>(h1, dw_w, fc2_w, fc2_b, out, b0);
  }
}

// Round 5
// 308.946 us; speedup vs baseline: 5.3420x; 1.4463x over previous
//
#include <hip/hip_runtime.h>

#define B_ 4
#define C_ 192
#define H_ 128
#define W_ 128
#define N_ (H_*W_)      // 16384
#define K_ 2048
#define HEADS_ 3
#define HD_ 64
#define HID_ 768
#define NC_ 4           // attention split-K chunks
#define KC_ (K_/NC_)    // 512

typedef __attribute__((ext_vector_type(4))) float f32x4;
typedef __attribute__((ext_vector_type(8))) short bf16x8;

__device__ __forceinline__ unsigned short f2bf(float f){
  unsigned int u = __float_as_uint(f);
  u += 0x7FFFu + ((u >> 16) & 1u);
  return (unsigned short)(u >> 16);
}
__device__ __forceinline__ float bf2f(unsigned short s){
  return __uint_as_float(((unsigned int)s) << 16);
}

__device__ __forceinline__ int load_idx(const unsigned* __restrict__ ip, int pos){
  bool is64 = (ip[1]==0u) & (ip[3]==0u) & (ip[5]==0u) & (ip[7]==0u);
  int v = is64 ? (int)ip[2*pos] : (int)ip[pos];
  return min(max(v, 0), N_-1);
}

// ---------------- LN1: x (B,C,N) -> y (nb,N,C); 256 thr, 4-way C-split ----------------
__global__ __launch_bounds__(256) void k_ln1(const float* __restrict__ x,
    const float* __restrict__ w, const float* __restrict__ bias,
    float* __restrict__ y, int b_off){
  int blk = blockIdx.x;
  int bl = blk >> 8;
  int b  = b_off + bl;
  int n0 = (blk & 255) * 64;
  int t  = threadIdx.x;
  int tok = t & 63, q = t >> 6;
  __shared__ float tile[64][C_+1];
  __shared__ float red[8][64];
  __shared__ float wls[C_], bls[C_];
  if (t < C_){ wls[t] = w[t]; bls[t] = bias[t]; }
  const float* xb = x + (size_t)b*C_*N_ + n0;
  float sum = 0.f, sq = 0.f;
#pragma unroll
  for (int i = 0; i < 48; ++i){
    int c = q + 4*i;
    float v = xb[(size_t)c*N_ + tok];
    tile[tok][c] = v;
    sum += v; sq += v*v;
  }
  red[q][tok] = sum; red[4+q][tok] = sq;
  __syncthreads();
  if (q == 0){
    float s  = red[0][tok]+red[1][tok]+red[2][tok]+red[3][tok];
    float s2 = red[4][tok]+red[5][tok]+red[6][tok]+red[7][tok];
    float mu = s*(1.f/C_);
    float rstd = rsqrtf(s2*(1.f/C_) - mu*mu + 1e-5f);
    red[0][tok] = mu; red[1][tok] = rstd;
  }
  __syncthreads();
  float* yb = y + ((size_t)bl*N_ + n0)*C_;
#pragma unroll
  for (int i = 0; i < 48; ++i){
    int li = t + 256*i;
    int tk = li / C_, c = li - tk*C_;
    yb[li] = (tile[tk][c]-red[0][tk])*red[1][tk]*wls[c] + bls[c];
  }
}

// ---------------- QKV MFMA GEMM with gather ----------------
__global__ __launch_bounds__(256) void k_qkv(const float* __restrict__ y,
    const unsigned* __restrict__ idx, const float* __restrict__ wq,
    unsigned short* __restrict__ qkv, int b_off){
  const int NT = (3*C_)/64;  // 9
  int bid = blockIdx.x;
  int bl  = bid / (16*NT);
  int rem = bid % (16*NT);
  int m0  = (rem / NT) * 128;
  int n0  = (rem % NT) * 64;
  int t = threadIdx.x, lane = t & 63;
  int wv = t >> 6, wm = wv & 1, wn = wv >> 1;
  __shared__ unsigned short Al[128][40];
  __shared__ unsigned short Bl[64][40];
  __shared__ int rows[128];
  if (t < 128) rows[t] = load_idx(idx, (b_off+bl)*K_ + m0 + t);
  __syncthreads();
  f32x4 acc[4][2] = {};
  int l15 = lane & 15, lhi = lane >> 4;
  for (int k0 = 0; k0 < C_; k0 += 32){
    {
      int m = t >> 1;
      const float* src = y + ((size_t)bl*N_ + rows[m])*C_ + k0;
#pragma unroll
      for (int i = 0; i < 4; ++i){
        int kq = (t & 1) + 2*i;
        float4 v = *reinterpret_cast<const float4*>(src + 4*kq);
        ushort4 p; p.x=f2bf(v.x); p.y=f2bf(v.y); p.z=f2bf(v.z); p.w=f2bf(v.w);
        *reinterpret_cast<ushort4*>(&Al[m][4*kq]) = p;
      }
      int n = t >> 2;
      const float* bsrc = wq + (size_t)(n0+n)*C_ + k0;
#pragma unroll
      for (int i = 0; i < 2; ++i){
        int q = (t & 3) + 4*i;
        float4 v = *reinterpret_cast<const float4*>(bsrc + 4*q);
        ushort4 p; p.x=f2bf(v.x); p.y=f2bf(v.y); p.z=f2bf(v.z); p.w=f2bf(v.w);
        *reinterpret_cast<ushort4*>(&Bl[n][4*q]) = p;
      }
    }
    __syncthreads();
    bf16x8 af[4], bfr[2];
#pragma unroll
    for (int mf = 0; mf < 4; ++mf)
      af[mf] = *reinterpret_cast<const bf16x8*>(&Al[wm*64 + mf*16 + l15][lhi*8]);
#pragma unroll
    for (int nf = 0; nf < 2; ++nf)
      bfr[nf] = *reinterpret_cast<const bf16x8*>(&Bl[wn*32 + nf*16 + l15][lhi*8]);
#pragma unroll
    for (int mf = 0; mf < 4; ++mf)
#pragma unroll
      for (int nf = 0; nf < 2; ++nf)
        acc[mf][nf] = __builtin_amdgcn_mfma_f32_16x16x32_bf16(af[mf], bfr[nf], acc[mf][nf], 0,0,0);
    __syncthreads();
  }
#pragma unroll
  for (int mf = 0; mf < 4; ++mf){
    int mb = m0 + wm*64 + mf*16 + lhi*4;
#pragma unroll
    for (int nf = 0; nf < 2; ++nf){
      int n = n0 + wn*32 + nf*16 + l15;
#pragma unroll
      for (int r = 0; r < 4; ++r)
        qkv[((size_t)bl*K_ + mb + r)*(3*C_) + n] = f2bf(acc[mf][nf][r]);
    }
  }
}

// ------- attention split-K: block=(bl,h,64 q rows, chunk c), 4 waves -------
__global__ __launch_bounds__(256) void k_attn(const unsigned short* __restrict__ qkv,
    float* __restrict__ po, float* __restrict__ pml, int nb){
  int bid = blockIdx.x;
  int c   = bid & (NC_-1);
  int qt  = (bid >> 2) & 31;
  int bh  = bid >> 7;
  int h = bh % HEADS_, bl = bh / HEADS_;
  int q0 = qt*64;
  int t = threadIdx.x, lane = t & 63, wv = t >> 6;
  int l15 = lane & 15, lhi = lane >> 4;
  const unsigned short* base = qkv + (size_t)bl*K_*(3*C_) + h*HD_;
  __shared__ unsigned short Ql[64][72];
  __shared__ unsigned short Kl[64][72];
  __shared__ unsigned short Vt[64][72];
  __shared__ unsigned short Pl[4][16][72];
  {
    int r = t >> 2, d0 = (t & 3) * 16;
    const uint4* src = reinterpret_cast<const uint4*>(base + (size_t)(q0+r)*(3*C_) + d0);
    *reinterpret_cast<uint4*>(&Ql[r][d0])   = src[0];
    *reinterpret_cast<uint4*>(&Ql[r][d0+8]) = src[1];
  }
  __syncthreads();
  float m_st[4] = {-1e30f,-1e30f,-1e30f,-1e30f};
  float l_st[4] = {0.f,0.f,0.f,0.f};
  f32x4 o[4] = {};
  for (int kt0 = c*KC_; kt0 < c*KC_ + KC_; kt0 += 64){
    {
      int r = t >> 2, d0 = (t & 3) * 16;
      const uint4* src = reinterpret_cast<const uint4*>(base + (size_t)(kt0+r)*(3*C_) + C_ + d0);
      *reinterpret_cast<uint4*>(&Kl[r][d0])   = src[0];
      *reinterpret_cast<uint4*>(&Kl[r][d0+8]) = src[1];
      int kp = t & 31, vd0 = (t >> 5) * 8, k = 2*kp;
      const ushort4* v0 = reinterpret_cast<const ushort4*>(base + (size_t)(kt0+k)*(3*C_)   + 2*C_ + vd0);
      const ushort4* v1 = reinterpret_cast<const ushort4*>(base + (size_t)(kt0+k+1)*(3*C_) + 2*C_ + vd0);
      ushort4 a0 = v0[0], a1 = v0[1], b0 = v1[0], b1 = v1[1];
      unsigned short va[8] = {a0.x,a0.y,a0.z,a0.w,a1.x,a1.y,a1.z,a1.w};
      unsigned short vb[8] = {b0.x,b0.y,b0.z,b0.w,b1.x,b1.y,b1.z,b1.w};
#pragma unroll
      for (int j = 0; j < 8; ++j){
        unsigned u = (unsigned)va[j] | ((unsigned)vb[j] << 16);
        *reinterpret_cast<unsigned*>(&Vt[vd0+j][k]) = u;
      }
    }
    __syncthreads();
    f32x4 s[4] = {};
#pragma unroll
    for (int kt = 0; kt < 2; ++kt){
      bf16x8 af = *reinterpret_cast<const bf16x8*>(&Ql[wv*16 + l15][kt*32 + lhi*8]);
#pragma unroll
      for (int nt = 0; nt < 4; ++nt){
        bf16x8 bfr = *reinterpret_cast<const bf16x8*>(&Kl[nt*16 + l15][kt*32 + lhi*8]);
        s[nt] = __builtin_amdgcn_mfma_f32_16x16x32_bf16(af, bfr, s[nt], 0,0,0);
      }
    }
    float corr[4];
#pragma unroll
    for (int reg = 0; reg < 4; ++reg){
      float a0 = s[0][reg]*0.125f, a1 = s[1][reg]*0.125f;
      float a2 = s[2][reg]*0.125f, a3 = s[3][reg]*0.125f;
      float mx = fmaxf(fmaxf(a0,a1), fmaxf(a2,a3));
      mx = fmaxf(mx, __shfl_xor(mx, 1));
      mx = fmaxf(mx, __shfl_xor(mx, 2));
      mx = fmaxf(mx, __shfl_xor(mx, 4));
      mx = fmaxf(mx, __shfl_xor(mx, 8));
      float mn = fmaxf(m_st[reg], mx);
      float cr = __expf(m_st[reg] - mn);
      float p0 = __expf(a0 - mn), p1 = __expf(a1 - mn);
      float p2 = __expf(a2 - mn), p3 = __expf(a3 - mn);
      float ls = p0 + p1 + p2 + p3;
      ls += __shfl_xor(ls, 1);
      ls += __shfl_xor(ls, 2);
      ls += __shfl_xor(ls, 4);
      ls += __shfl_xor(ls, 8);
      l_st[reg] = l_st[reg]*cr + ls;
      m_st[reg] = mn; corr[reg] = cr;
      int row = lhi*4 + reg;
      float q0v = __shfl_xor(p0, 1), q1v = __shfl_xor(p1, 1);
      float q2v = __shfl_xor(p2, 1), q3v = __shfl_xor(p3, 1);
      int e = l15 & ~1;
      unsigned uA, uB; int cA, cB;
      if (!(l15 & 1)){
        uA = (unsigned)f2bf(p0) | ((unsigned)f2bf(q0v) << 16); cA = e;
        uB = (unsigned)f2bf(p2) | ((unsigned)f2bf(q2v) << 16); cB = 32 + e;
      } else {
        uA = (unsigned)f2bf(q1v) | ((unsigned)f2bf(p1) << 16); cA = 16 + e;
        uB = (unsigned)f2bf(q3v) | ((unsigned)f2bf(p3) << 16); cB = 48 + e;
      }
      *reinterpret_cast<unsigned*>(&Pl[wv][row][cA]) = uA;
      *reinterpret_cast<unsigned*>(&Pl[wv][row][cB]) = uB;
    }
    __threadfence_block();
#pragma unroll
    for (int nt = 0; nt < 4; ++nt)
#pragma unroll
      for (int reg = 0; reg < 4; ++reg)
        o[nt][reg] *= corr[reg];
#pragma unroll
    for (int kt = 0; kt < 2; ++kt){
      bf16x8 pa = *reinterpret_cast<const bf16x8*>(&Pl[wv][l15][kt*32 + lhi*8]);
#pragma unroll
      for (int nt = 0; nt < 4; ++nt){
        bf16x8 vb = *reinterpret_cast<const bf16x8*>(&Vt[nt*16 + l15][kt*32 + lhi*8]);
        o[nt] = __builtin_amdgcn_mfma_f32_16x16x32_bf16(pa, vb, o[nt], 0,0,0);
      }
    }
    __syncthreads();
  }
  int R = nb*HEADS_*K_;
  int rowb = (bl*HEADS_ + h)*K_;
#pragma unroll
  for (int reg = 0; reg < 4; ++reg){
    int rq = rowb + q0 + wv*16 + lhi*4 + reg;
#pragma unroll
    for (int nt = 0; nt < 4; ++nt)
      po[((size_t)c*R + rq)*HD_ + nt*16 + l15] = o[nt][reg];
    if (l15 == 0)
      *reinterpret_cast<float2*>(pml + 2*((size_t)c*R + rq)) =
          make_float2(m_st[reg], l_st[reg]);
  }
}

// ---------------- merge split-K partials -> ao bf16 (bl,K,C) ----------------
__global__ __launch_bounds__(256) void k_amerge(const float* __restrict__ po,
    const float* __restrict__ pml, unsigned short* __restrict__ ao, int nb){
  int R = nb*HEADS_*K_;
  int row = blockIdx.x*4 + (threadIdx.x >> 6);
  int lane = threadIdx.x & 63;
  float m[NC_], l[NC_];
#pragma unroll
  for (int cc = 0; cc < NC_; ++cc){
    float2 v = *reinterpret_cast<const float2*>(pml + 2*((size_t)cc*R + row));
    m[cc] = v.x; l[cc] = v.y;
  }
  float M = fmaxf(fmaxf(m[0],m[1]), fmaxf(m[2],m[3]));
  float L = 0.f, o = 0.f;
#pragma unroll
  for (int cc = 0; cc < NC_; ++cc){
    float e = __expf(m[cc] - M);
    L += l[cc]*e;
    o += e * po[((size_t)cc*R + row)*HD_ + lane];
  }
  o /= L;
  int q = row & (K_-1);
  int bh = row >> 11;
  int h = bh % HEADS_, bl = bh / HEADS_;
  ao[((size_t)bl*K_ + q)*C_ + h*HD_ + lane] = f2bf(o);
}

// ---------------- proj MFMA GEMM + scatter into y (fp32) ----------------
__global__ __launch_bounds__(256) void k_proj(const unsigned short* __restrict__ ain,
    const unsigned* __restrict__ idx, const float* __restrict__ pw,
    const float* __restrict__ pb, float* __restrict__ y, int b_off){
  const int NT = C_/64;   // 3
  int bid = blockIdx.x;
  int bl  = bid / (16*NT);
  int rem = bid % (16*NT);
  int m0  = (rem / NT) * 128;
  int n0  = (rem % NT) * 64;
  int t = threadIdx.x, lane = t & 63;
  int wv = t >> 6, wm = wv & 1, wn = wv >> 1;
  __shared__ unsigned short Al[128][40];
  __shared__ unsigned short Bl[64][40];
  __shared__ int rows[128];
  if (t < 128) rows[t] = load_idx(idx, (b_off+bl)*K_ + m0 + t);
  __syncthreads();
  f32x4 acc[4][2] = {};
  int l15 = lane & 15, lhi = lane >> 4;
  for (int k0 = 0; k0 < C_; k0 += 32){
    {
      int m = t >> 1;
      const unsigned short* src = ain + ((size_t)bl*K_ + m0 + m)*C_ + k0;
#pragma unroll
      for (int i = 0; i < 4; ++i){
        int kq = (t & 1) + 2*i;
        *reinterpret_cast<ushort4*>(&Al[m][4*kq]) =
            *reinterpret_cast<const ushort4*>(src + 4*kq);
      }
      int n = t >> 2;
      const float* bsrc = pw + (size_t)(n0+n)*C_ + k0;
#pragma unroll
      for (int i = 0; i < 2; ++i){
        int q = (t & 3) + 4*i;
        float4 v = *reinterpret_cast<const float4*>(bsrc + 4*q);
        ushort4 p; p.x=f2bf(v.x); p.y=f2bf(v.y); p.z=f2bf(v.z); p.w=f2bf(v.w);
        *reinterpret_cast<ushort4*>(&Bl[n][4*q]) = p;
      }
    }
    __syncthreads();
    bf16x8 af[4], bfr[2];
#pragma unroll
    for (int mf = 0; mf < 4; ++mf)
      af[mf] = *reinterpret_cast<const bf16x8*>(&Al[wm*64 + mf*16 + l15][lhi*8]);
#pragma unroll
    for (int nf = 0; nf < 2; ++nf)
      bfr[nf] = *reinterpret_cast<const bf16x8*>(&Bl[wn*32 + nf*16 + l15][lhi*8]);
#pragma unroll
    for (int mf = 0; mf < 4; ++mf)
#pragma unroll
      for (int nf = 0; nf < 2; ++nf)
        acc[mf][nf] = __builtin_amdgcn_mfma_f32_16x16x32_bf16(af[mf], bfr[nf], acc[mf][nf], 0,0,0);
    __syncthreads();
  }
#pragma unroll
  for (int mf = 0; mf < 4; ++mf){
    int mb = wm*64 + mf*16 + lhi*4;
#pragma unroll
    for (int nf = 0; nf < 2; ++nf){
      int n = n0 + wn*32 + nf*16 + l15;
      float bv = pb[n];
#pragma unroll
      for (int r = 0; r < 4; ++r)
        y[((size_t)bl*N_ + rows[mb + r])*C_ + n] = acc[mf][nf][r] + bv;
    }
  }
}

// ---------------- residual + LN2 -> ln2t (B,C,N) [== d_out]; 256 thr ----------------
__global__ __launch_bounds__(256) void k_ln2(const float* __restrict__ x,
    const float* __restrict__ y, const float* __restrict__ w,
    const float* __restrict__ bias, float* __restrict__ ln2t, int b_off){
  int blk = blockIdx.x;
  int bl = blk >> 8;
  int b  = b_off + bl;
  int n0 = (blk & 255) * 64;
  int t  = threadIdx.x;
  int tok = t & 63, q = t >> 6;
  __shared__ float tile[64][C_+1];
  __shared__ float red[8][64];
  __shared__ float wls[C_], bls[C_];
  if (t < C_){ wls[t] = w[t]; bls[t] = bias[t]; }
  const float* yb = y + ((size_t)bl*N_ + n0)*C_;
#pragma unroll
  for (int i = 0; i < 48; ++i){
    int li = t + 256*i;
    int tk = li / C_, c = li - tk*C_;
    tile[tk][c] = yb[li];
  }
  __syncthreads();
  const float* xb = x + (size_t)b*C_*N_ + n0;
  float sum = 0.f, sq = 0.f;
#pragma unroll
  for (int i = 0; i < 48; ++i){
    int c = q + 4*i;
    float v = xb[(size_t)c*N_ + tok] + tile[tok][c];
    tile[tok][c] = v;
    sum += v; sq += v*v;
  }
  red[q][tok] = sum; red[4+q][tok] = sq;
  __syncthreads();
  if (q == 0){
    float s  = red[0][tok]+red[1][tok]+red[2][tok]+red[3][tok];
    float s2 = red[4][tok]+red[5][tok]+red[6][tok]+red[7][tok];
    float mu = s*(1.f/C_);
    float rstd = rsqrtf(s2*(1.f/C_) - mu*mu + 1e-5f);
    red[0][tok] = mu; red[1][tok] = rstd;
  }
  __syncthreads();
  float* ob = ln2t + (size_t)b*C_*N_ + n0;
  float mu = red[0][tok], rstd = red[1][tok];
#pragma unroll
  for (int i = 0; i < 48; ++i){
    int c = q + 4*i;
    ob[(size_t)c*N_ + tok] = (tile[tok][c]-mu)*rstd*wls[c] + bls[c];
  }
}

// ------- fc1 MFMA, A-reuse: per block one 128-token m-tile, loop 12 n-tiles -------
__global__ __launch_bounds__(256) void k_fc1(const float* __restrict__ ln2t,
    const float* __restrict__ wgt, const float* __restrict__ bias,
    unsigned short* __restrict__ h1, int b_off){
  int bid = blockIdx.x;
  int bl  = bid >> 7;
  int m0  = (bid & 127) * 128;
  int t = threadIdx.x, lane = t & 63;
  int wv = t >> 6, wm = wv & 1, wn = wv >> 1;
  int l15 = lane & 15, lhi = lane >> 4;
  __shared__ unsigned short Al[128][200];   // [m][c] bf16, stride 400B (25x16B)
  __shared__ unsigned short Bl[64][200];
  const float* a = ln2t + (size_t)(b_off+bl)*C_*N_ + m0;
  unsigned short* hb = h1 + (size_t)bl*HID_*N_;
  {
    int m = t & 127, half = t >> 7;
#pragma unroll
    for (int i = 0; i < 48; ++i){
      int p = half + 2*i;                    // 0..95
      float v0 = a[(size_t)(2*p)*N_ + m];
      float v1 = a[(size_t)(2*p+1)*N_ + m];
      unsigned u = (unsigned)f2bf(v0) | ((unsigned)f2bf(v1) << 16);
      *reinterpret_cast<unsigned*>(&Al[m][2*p]) = u;
    }
  }
  for (int nt = 0; nt < 12; ++nt){
    int n0 = nt*64;
    __syncthreads();
    {
      int n = t >> 2;
#pragma unroll
      for (int i = 0; i < 12; ++i){
        int q = (t & 3) + 4*i;
        float4 v = *reinterpret_cast<const float4*>(wgt + (size_t)(n0+n)*C_ + 4*q);
        ushort4 p; p.x=f2bf(v.x); p.y=f2bf(v.y); p.z=f2bf(v.z); p.w=f2bf(v.w);
        *reinterpret_cast<ushort4*>(&Bl[n][4*q]) = p;
      }
    }
    __syncthreads();
    f32x4 acc[4][2] = {};
#pragma unroll
    for (int ks = 0; ks < 6; ++ks){
      bf16x8 af[4], bfr[2];
#pragma unroll
      for (int mf = 0; mf < 4; ++mf)
        af[mf] = *reinterpret_cast<const bf16x8*>(&Al[wm*64 + mf*16 + l15][ks*32 + lhi*8]);
#pragma unroll
      for (int nf = 0; nf < 2; ++nf)
        bfr[nf] = *reinterpret_cast<const bf16x8*>(&Bl[wn*32 + nf*16 + l15][ks*32 + lhi*8]);
#pragma unroll
      for (int mf = 0; mf < 4; ++mf)
#pragma unroll
        for (int nf = 0; nf < 2; ++nf)
          acc[mf][nf] = __builtin_amdgcn_mfma_f32_16x16x32_bf16(af[mf], bfr[nf], acc[mf][nf], 0,0,0);
    }
#pragma unroll
    for (int mf = 0; mf < 4; ++mf){
      int mb = m0 + wm*64 + mf*16 + lhi*4;
#pragma unroll
      for (int nf = 0; nf < 2; ++nf){
        int n = n0 + wn*32 + nf*16 + l15;
        float bv = bias[n];
        ushort4 pk;
        pk.x = f2bf(acc[mf][nf][0] + bv);
        pk.y = f2bf(acc[mf][nf][1] + bv);
        pk.z = f2bf(acc[mf][nf][2] + bv);
        pk.w = f2bf(acc[mf][nf][3] + bv);
        *reinterpret_cast<ushort4*>(&hb[(size_t)n*N_ + mb]) = pk;
      }
    }
  }
}

// ------- fused depthwise3x3+GELU+fc2+residual, dbuf-prefetched h1 staging -------
__global__ __launch_bounds__(512, 1) void k_fc2f(const unsigned short* __restrict__ h1,
    const float* __restrict__ dw, const float* __restrict__ wgt,
    const float* __restrict__ bias, float* __restrict__ out, int b_off){
  int bid = blockIdx.x;
  int r2  = bid & 63;
  int bl  = bid >> 6;
  int b   = b_off + bl;
  int r0  = r2*2;
  int m0  = r0*W_;
  int t = threadIdx.x, lane = t & 63, wv = t >> 6;
  int wm = wv & 3, wn = wv >> 2;
  int l15 = lane & 15, lhi = lane >> 4;
  __shared__ uint4 HsU[2*2048];                 // 64 KB: 2 x [4 rows][32 ch][128 col] bf16
  __shared__ unsigned char Alr[256*96 + 64];    // 24.6 KB
  __shared__ unsigned short Bl[192][40];        // 15.4 KB
  __shared__ float Dwl[HID_*9];                 // 27.6 KB
  char* Hsb = (char*)HsU;
  const unsigned short* h1b = h1 + (size_t)bl*HID_*N_;
  for (int i = t; i < HID_*9; i += 512) Dwl[i] = dw[i];
  int cch = t & 31, strip = t >> 5;
  int lr = strip >> 3, j0 = (strip & 7) * 16;
  int xr = (cch & 15) << 4;
  uint4 hreg[4];
  auto hload = [&](int k0n){
#pragma unroll
    for (int i = 0; i < 4; ++i){
      int li = t + 512*i;
      int hrow = li >> 9, rem = li & 511, ch = rem >> 4, seg = rem & 15;
      int rr = r0 - 1 + hrow; rr = rr < 0 ? 0 : (rr > H_-1 ? H_-1 : rr);
      hreg[i] = *reinterpret_cast<const uint4*>(h1b + (size_t)(k0n+ch)*N_ + rr*W_ + seg*8);
    }
  };
  auto hwrite = [&](int buf){
#pragma unroll
    for (int i = 0; i < 4; ++i){
      int li = t + 512*i;
      int hrow = li >> 9, rem = li & 511, ch = rem >> 4, seg = rem & 15;
      int byte = (((hrow*32 + ch)*128 + seg*8)*2) ^ ((ch & 15) << 4);
      *reinterpret_cast<uint4*>(Hsb + buf*32768 + byte) = hreg[i];
    }
  };
  hload(0); hwrite(0);
  f32x4 acc[4][6] = {};
  for (int c = 0; c < 24; ++c){
    int k0 = c*32, cur = c & 1;
    __syncthreads();                     // Hs[cur]+Bl/Alr hazards cleared
    if (c < 23) hload(k0 + 32);          // prefetch next chunk into regs
    // stage Bl (fc2_w slice, L2-hot)
#pragma unroll
    for (int i = 0; i < 3; ++i){
      int li = t + 512*i;
      int row = li >> 3, q = li & 7;
      float4 v = *reinterpret_cast<const float4*>(wgt + (size_t)row*HID_ + k0 + 4*q);
      ushort4 p; p.x=f2bf(v.x); p.y=f2bf(v.y); p.z=f2bf(v.z); p.w=f2bf(v.w);
      *reinterpret_cast<ushort4*>(&Bl[row][4*q]) = p;
    }
    // conv 3x3 + GELU -> Alr (1 ch x 16 cols per thread)
    {
      const char* hs = Hsb + cur*32768;
      const float* wp = &Dwl[(k0+cch)*9];
      float s[16];
#pragma unroll
      for (int j = 0; j < 16; ++j) s[j] = 0.f;
#pragma unroll
      for (int dy = 0; dy < 3; ++dy){
        int rr = r0 - 1 + lr + dy;
        if (rr < 0 || rr >= H_) continue;
        int rowb = ((lr+dy)*32 + cch) << 8;
        bf16x8 Av = *reinterpret_cast<const bf16x8*>(hs + rowb + ((j0*2) ^ xr));
        bf16x8 Bv = *reinterpret_cast<const bf16x8*>(hs + rowb + (((j0+8)*2) ^ xr));
        float v[18];
        v[0]  = (j0 > 0)   ? bf2f(*reinterpret_cast<const unsigned short*>(hs + rowb + (((j0-1)*2) ^ xr)))  : 0.f;
        v[17] = (j0 < 112) ? bf2f(*reinterpret_cast<const unsigned short*>(hs + rowb + (((j0+16)*2) ^ xr))) : 0.f;
#pragma unroll
        for (int j = 0; j < 8; ++j){
          v[1+j] = bf2f((unsigned short)Av[j]);
          v[9+j] = bf2f((unsigned short)Bv[j]);
        }
        float wa = wp[3*dy], wb2 = wp[3*dy+1], wc2 = wp[3*dy+2];
#pragma unroll
        for (int j = 0; j < 16; ++j)
          s[j] += v[j]*wa + v[j+1]*wb2 + v[j+2]*wc2;
      }
#pragma unroll
      for (int j = 0; j < 16; ++j){
        float xx = s[j];
        float ge = 0.5f*xx*(1.f + erff(xx*0.70710678f));
        int col = lr*128 + j0 + j;
        int byte = col*96 + ((col >> 3) & 1)*64 + cch*2;
        *reinterpret_cast<unsigned short*>(Alr + byte) = f2bf(ge);
      }
    }
    if (c < 23) hwrite(cur ^ 1);         // write prefetched chunk to other buffer
    __syncthreads();                     // Alr + Bl + Hs[nxt] visible
    bf16x8 af[4], bfr[6];
#pragma unroll
    for (int mf = 0; mf < 4; ++mf){
      int row = wm*64 + mf*16 + l15;
      int byte = row*96 + ((row >> 3) & 1)*64 + lhi*16;
      af[mf] = *reinterpret_cast<const bf16x8*>(Alr + byte);
    }
#pragma unroll
    for (int nf = 0; nf < 6; ++nf)
      bfr[nf] = *reinterpret_cast<const bf16x8*>(&Bl[wn*96 + nf*16 + l15][lhi*8]);
#pragma unroll
    for (int mf = 0; mf < 4; ++mf)
#pragma unroll
      for (int nf = 0; nf < 6; ++nf)
        acc[mf][nf] = __builtin_amdgcn_mfma_f32_16x16x32_bf16(af[mf], bfr[nf], acc[mf][nf], 0,0,0);
  }
  // epilogue: += bias + residual (out holds ln2t)
#pragma unroll
  for (int mf = 0; mf < 4; ++mf){
    int tok = m0 + wm*64 + mf*16 + lhi*4;
#pragma unroll
    for (int nf = 0; nf < 6; ++nf){
      int oc = wn*96 + nf*16 + l15;
      float bv = bias[oc];
      size_t off = ((size_t)b*C_ + oc)*N_ + tok;
      float4 rr = *reinterpret_cast<const float4*>(out + off);
      float4 v = make_float4(rr.x + acc[mf][nf][0] + bv, rr.y + acc[mf][nf][1] + bv,
                             rr.z + acc[mf][nf][2] + bv, rr.w + acc[mf][nf][3] + bv);
      *reinterpret_cast<float4*>(out + off) = v;
    }
  }
}

extern "C" void kernel_launch(void* const* d_in, const int* in_sizes, int n_in,
                              void* d_out, int out_size, void* d_ws, size_t ws_size,
                              hipStream_t stream) {
  const float*    x      = (const float*)d_in[0];
  const unsigned* idx    = (const unsigned*)d_in[1];
  const float*    ln1_w  = (const float*)d_in[2];
  const float*    ln1_b  = (const float*)d_in[3];
  const float*    qkv_w  = (const float*)d_in[4];
  const float*    proj_w = (const float*)d_in[5];
  const float*    proj_b = (const float*)d_in[6];
  const float*    ln2_w  = (const float*)d_in[7];
  const float*    ln2_b  = (const float*)d_in[8];
  const float*    fc1_w  = (const float*)d_in[9];
  const float*    fc1_b  = (const float*)d_in[10];
  const float*    dw_w   = (const float*)d_in[11];
  const float*    fc2_w  = (const float*)d_in[12];
  const float*    fc2_b  = (const float*)d_in[13];
  float* out = (float*)d_out;          // doubles as ln2t (B,C,N) f32

  const size_t SZY = (size_t)N_*C_*4;
  const size_t SZQ = (size_t)K_*3*C_*2;
  const size_t SZA = (size_t)K_*C_*2;
  const size_t SZO = (size_t)NC_*HEADS_*K_*HD_*4;
  const size_t SZH = (size_t)HID_*N_*2;            // 25.17 MB / batch
  int nb = (ws_size >= (size_t)B_*SZH) ? B_ : 1;   // deterministic

  char* ws = (char*)d_ws;
  float*          y    = (float*)ws;
  unsigned short* qkvb = (unsigned short*)(ws + (size_t)nb*SZY);
  unsigned short* aob  = (unsigned short*)(ws + (size_t)nb*(SZY+SZQ));
  float*          po   = (float*)(ws + (size_t)nb*(SZY+SZQ+SZA));
  float*          pml  = (float*)(ws + (size_t)nb*(SZY+SZQ+SZA+SZO));
  unsigned short* h1   = (unsigned short*)ws;      // MLP phase (front dead)

  for (int b0 = 0; b0 < B_; b0 += nb){
    k_ln1   <<<nb*256,             256, 0, stream>>>(x, ln1_w, ln1_b, y, b0);
    k_qkv   <<<nb*16*9,            256, 0, stream>>>(y, idx, qkv_w, qkvb, b0);
    k_attn  <<<nb*HEADS_*32*NC_,   256, 0, stream>>>(qkvb, po, pml, nb);
    k_amerge<<<nb*HEADS_*K_/4,     256, 0, stream>>>(po, pml, aob, nb);
    k_proj  <<<nb*16*3,            256, 0, stream>>>(aob, idx, proj_w, proj_b, y, b0);
    k_ln2   <<<nb*256,             256, 0, stream>>>(x, y, ln2_w, ln2_b, out, b0);
    k_fc1   <<<nb*128,             256, 0, stream>>>(out, fc1_w, fc1_b, h1, b0);
    k_fc2f  <<<nb*64,              512, 0, stream>>>(h1, dw_w, fc2_w, fc2_b, out, b0);
  }
}